// Round 2
// baseline (794.044 us; speedup 1.0000x reference)
//
#include <hip/hip_runtime.h>
#include <hip/hip_bf16.h>
#include <math.h>

typedef __bf16 bf16;
typedef __bf16 bf16x8 __attribute__((ext_vector_type(8)));
typedef __bf16 bf16x4 __attribute__((ext_vector_type(4)));
typedef float  f32x4  __attribute__((ext_vector_type(4)));

static constexpr int B_  = 2;
static constexpr int S_  = 2048;
static constexpr int D_  = 1024;
static constexpr int H_  = 16;
static constexpr int HD_ = 64;
static constexpr int I_  = 4096;
static constexpr int NT  = B_ * S_;       // 4096 tokens

// ---------- helpers ----------
__device__ __forceinline__ void atomicMaxF(float* p, float v) {
  // v >= 0 always (absmax), so uint bit-order == float order
  atomicMax((unsigned int*)p, __float_as_uint(v));
}

__device__ __forceinline__ f32x4 mfma16(bf16x8 a, bf16x8 b, f32x4 c) {
  return __builtin_amdgcn_mfma_f32_16x16x32_bf16(a, b, c, 0, 0, 0);
}

__device__ __forceinline__ void gload16(const void* g, void* lds) {
  // async global->LDS, 16B/lane; LDS dest = wave-uniform base + lane*16
  __builtin_amdgcn_global_load_lds(
      (const __attribute__((address_space(1))) void*)g,
      (__attribute__((address_space(3))) void*)lds, 16, 0, 0);
}

__device__ __forceinline__ float quant1(float x, float scale, float qmax) {
  // matches jnp: round(clip(x/scale,-qmax,qmax))*scale, RNE rounding
  return rintf(fminf(fmaxf(x / scale, -qmax), qmax)) * scale;
}

// ---------- scalar init ----------
__global__ void k_init(float* s) {
  if (threadIdx.x < 32) s[threadIdx.x] = 0.f;
}

// ---------- fused per-tensor absmax + quant for the 6 weights ----------
struct WArgs {
  const float* w[6];
  bf16* q[6];
  size_t n4[6];
};

__global__ __launch_bounds__(256) void k_absmax6(WArgs a, float* __restrict__ slots) {
  const int z = blockIdx.z;
  const float* __restrict__ x = a.w[z];
  const size_t n4 = a.n4[z];
  size_t i = (size_t)blockIdx.x * 256 + threadIdx.x;
  const size_t stride = (size_t)gridDim.x * 256;
  float m = 0.f;
  for (; i < n4; i += stride) {
    float4 v = ((const float4*)x)[i];
    m = fmaxf(m, fmaxf(fmaxf(fabsf(v.x), fabsf(v.y)), fmaxf(fabsf(v.z), fabsf(v.w))));
  }
  #pragma unroll
  for (int o = 32; o; o >>= 1) m = fmaxf(m, __shfl_xor(m, o));
  __shared__ float red[4];
  if ((threadIdx.x & 63) == 0) red[threadIdx.x >> 6] = m;
  __syncthreads();
  if (threadIdx.x == 0)
    atomicMaxF(slots + z, fmaxf(fmaxf(red[0], red[1]), fmaxf(red[2], red[3])));
}

__global__ __launch_bounds__(256) void k_quant6(WArgs a, const float* __restrict__ slots,
                                                const int* __restrict__ bits) {
  const int z = blockIdx.z;
  const float* __restrict__ x = a.w[z];
  bf16* __restrict__ y = a.q[z];
  const size_t n4 = a.n4[z];
  const float qmax  = (float)((1 << (*bits - 1)) - 1);
  const float scale = fmaxf(slots[z], 1e-8f) / qmax;
  size_t i = (size_t)blockIdx.x * 256 + threadIdx.x;
  const size_t stride = (size_t)gridDim.x * 256;
  for (; i < n4; i += stride) {
    float4 v = ((const float4*)x)[i];
    bf16x4 o;
    o[0] = (bf16)quant1(v.x, scale, qmax);
    o[1] = (bf16)quant1(v.y, scale, qmax);
    o[2] = (bf16)quant1(v.z, scale, qmax);
    o[3] = (bf16)quant1(v.w, scale, qmax);
    ((bf16x4*)y)[i] = o;
  }
}

// ---------- fake-quant fp32 -> bf16 (activations) ----------
__global__ __launch_bounds__(256) void k_quant(const float* __restrict__ x, bf16* __restrict__ y,
                                               const float* __restrict__ slot,
                                               const int* __restrict__ bits, size_t n4) {
  const float qmax  = (float)((1 << (*bits - 1)) - 1);
  const float scale = fmaxf(*slot, 1e-8f) / qmax;
  size_t i = (size_t)blockIdx.x * 256 + threadIdx.x;
  const size_t stride = (size_t)gridDim.x * 256;
  for (; i < n4; i += stride) {
    float4 v = ((const float4*)x)[i];
    bf16x4 o;
    o[0] = (bf16)quant1(v.x, scale, qmax);
    o[1] = (bf16)quant1(v.y, scale, qmax);
    o[2] = (bf16)quant1(v.z, scale, qmax);
    o[3] = (bf16)quant1(v.w, scale, qmax);
    ((bf16x4*)y)[i] = o;
  }
}

// ---------- fake-quant bf16 in-place (GELU output) ----------
__global__ __launch_bounds__(256) void k_quant_ip(bf16* __restrict__ x,
                                                  const float* __restrict__ slot,
                                                  const int* __restrict__ bits, size_t n8) {
  const float qmax  = (float)((1 << (*bits - 1)) - 1);
  const float scale = fmaxf(*slot, 1e-8f) / qmax;
  size_t i = (size_t)blockIdx.x * 256 + threadIdx.x;
  if (i >= n8) return;
  bf16x8 v = ((const bf16x8*)x)[i];
  #pragma unroll
  for (int j = 0; j < 8; j++) v[j] = (bf16)quant1((float)v[j], scale, qmax);
  ((bf16x8*)x)[i] = v;
}

// ---------- LayerNorm (fp32 out, + absmax) : one block per row ----------
__global__ __launch_bounds__(256) void k_ln(const float* __restrict__ x, const float* __restrict__ g,
                                            const float* __restrict__ be, float* __restrict__ y,
                                            float* __restrict__ slot) {
  const int row = blockIdx.x, t = threadIdx.x;
  const float4 v = ((const float4*)(x + (size_t)row * D_))[t];
  float s = v.x + v.y + v.z + v.w;
  float q = v.x * v.x + v.y * v.y + v.z * v.z + v.w * v.w;
  #pragma unroll
  for (int o = 32; o; o >>= 1) { s += __shfl_xor(s, o); q += __shfl_xor(q, o); }
  __shared__ float red[8];
  const int wid = t >> 6;
  if ((t & 63) == 0) { red[wid] = s; red[4 + wid] = q; }
  __syncthreads();
  s = red[0] + red[1] + red[2] + red[3];
  q = red[4] + red[5] + red[6] + red[7];
  const float mean = s * (1.f / D_);
  const float rstd = rsqrtf(q * (1.f / D_) - mean * mean + 1e-5f);
  const float4 gv = ((const float4*)g)[t];
  const float4 bv = ((const float4*)be)[t];
  float4 o;
  o.x = (v.x - mean) * rstd * gv.x + bv.x;
  o.y = (v.y - mean) * rstd * gv.y + bv.y;
  o.z = (v.z - mean) * rstd * gv.z + bv.z;
  o.w = (v.w - mean) * rstd * gv.w + bv.w;
  ((float4*)(y + (size_t)row * D_))[t] = o;
  float m = fmaxf(fmaxf(fabsf(o.x), fabsf(o.y)), fmaxf(fabsf(o.z), fabsf(o.w)));
  #pragma unroll
  for (int oo = 32; oo; oo >>= 1) m = fmaxf(m, __shfl_xor(m, oo));
  __syncthreads();                 // red reuse
  if ((t & 63) == 0) red[wid] = m;
  __syncthreads();
  if (t == 0) atomicMaxF(slot, fmaxf(fmaxf(red[0], red[1]), fmaxf(red[2], red[3])));
}

// ---------- GEMM: C[M,N] = A[M,K] @ B[N,K]^T (+bias, +mode epilogue) ----------
// 128x128 tile, BK=32, 4 waves in 2x2, each wave 64x64 = 4x4 mfma_16x16x32 frags.
struct GemmArgs {
  const bf16* A;
  const bf16* B0; const bf16* B1; const bf16* B2;
  const float* bias0; const float* bias1; const float* bias2;
  void* out0; void* out1; void* out2;
  const float* res;   // MODE 1: residual (fp32, same layout as out)
  float* slot;        // MODE 2: absmax slot
  int K; int ldc;
};

// MODE 0: bf16 out (+bias), 3-way select by blockIdx.z (QKV fused);
//         z==2 (V) stores TRANSPOSED: [b][col][s] for attention's PV B-operand
// MODE 1: f32 out = acc + bias + res
// MODE 2: bf16 out = gelu(acc+bias), absmax -> slot
template <int MODE>
__global__ __launch_bounds__(256) void k_gemm(GemmArgs a) {
  __shared__ __align__(16) bf16 As[128 * 32];
  __shared__ __align__(16) bf16 Bs[128 * 32];
  const int t = threadIdx.x, wid = t >> 6, lane = t & 63;
  const int grp = lane >> 4, l15 = lane & 15;
  const int wm = wid >> 1, wn = wid & 1;
  const size_t m0 = (size_t)blockIdx.x * 128, n0 = (size_t)blockIdx.y * 128;
  const int K = a.K, ldc = a.ldc;

  const bf16* Bw; const float* bias; void* outv;
  if constexpr (MODE == 0) {
    const int z = blockIdx.z;
    Bw   = z == 0 ? a.B0 : (z == 1 ? a.B1 : a.B2);
    bias = z == 0 ? a.bias0 : (z == 1 ? a.bias1 : a.bias2);
    outv = z == 0 ? a.out0 : (z == 1 ? a.out1 : a.out2);
  } else {
    Bw = a.B0; bias = a.bias0; outv = a.out0;
  }

  const f32x4 zero = {0.f, 0.f, 0.f, 0.f};
  f32x4 acc[4][4];
  #pragma unroll
  for (int m = 0; m < 4; m++)
    #pragma unroll
    for (int n = 0; n < 4; n++) acc[m][n] = zero;

  for (int kt = 0; kt < K; kt += 32) {
    // stage A,B tiles (8KB each): 4 waves x 2 rounds x 1KB
    #pragma unroll
    for (int r = 0; r < 2; r++) {
      const int ob  = (wid * 2 + r) * 1024 + lane * 16;  // byte in tile
      const int row = ob >> 6;                            // 64B per row (32 bf16)
      const int col = (ob & 63) >> 1;
      gload16(a.A + (m0 + row) * (size_t)K + (kt + col), (char*)As + (size_t)(wid * 2 + r) * 1024);
      gload16(Bw  + (n0 + row) * (size_t)K + (kt + col), (char*)Bs + (size_t)(wid * 2 + r) * 1024);
    }
    __syncthreads();   // drains vmcnt (global_load_lds) + lgkm
    bf16x8 af[4], bfv[4];
    #pragma unroll
    for (int m = 0; m < 4; m++)
      af[m] = *(const bf16x8*)(As + (wm * 64 + m * 16 + l15) * 32 + grp * 8);
    #pragma unroll
    for (int n = 0; n < 4; n++)
      bfv[n] = *(const bf16x8*)(Bs + (wn * 64 + n * 16 + l15) * 32 + grp * 8);
    #pragma unroll
    for (int m = 0; m < 4; m++)
      #pragma unroll
      for (int n = 0; n < 4; n++)
        acc[m][n] = mfma16(af[m], bfv[n], acc[m][n]);
    __syncthreads();   // protect LDS before next stage
  }

  // epilogue: C/D frag layout: row=(lane>>4)*4+i, col=lane&15
  const size_t gr0 = m0 + wm * 64 + grp * 4;
  const size_t gc0 = n0 + wn * 64 + l15;

  if constexpr (MODE == 0) {
    if (blockIdx.z == 2) {
      // V^T store: out[b][gc][s] packed bf16x4 along s (i dimension)
      #pragma unroll
      for (int n = 0; n < 4; n++) {
        const size_t gc = gc0 + n * 16;
        const float bc = bias[gc];
        #pragma unroll
        for (int m = 0; m < 4; m++) {
          const size_t gr = gr0 + m * 16;              // tokens gr..gr+3, same batch
          const size_t bb = gr >> 11, s0 = gr & (S_ - 1);
          bf16x4 vv;
          #pragma unroll
          for (int i = 0; i < 4; i++) vv[i] = (bf16)(acc[m][n][i] + bc);
          *(bf16x4*)((bf16*)outv + bb * (size_t)D_ * S_ + gc * S_ + s0) = vv;
        }
      }
      return;
    }
  }

  float lmax = 0.f;
  #pragma unroll
  for (int n = 0; n < 4; n++) {
    const size_t gc = gc0 + n * 16;
    const float bc = bias[gc];
    #pragma unroll
    for (int m = 0; m < 4; m++) {
      const size_t gr = gr0 + m * 16;
      #pragma unroll
      for (int i = 0; i < 4; i++) {
        const float v = acc[m][n][i] + bc;
        const size_t idx = (gr + i) * (size_t)ldc + gc;
        if constexpr (MODE == 0) {
          ((bf16*)outv)[idx] = (bf16)v;
        } else if constexpr (MODE == 1) {
          ((float*)outv)[idx] = v + a.res[idx];
        } else {
          const float gl = 0.5f * v * (1.0f + erff(v * 0.7071067811865475f));
          ((bf16*)outv)[idx] = (bf16)gl;
          lmax = fmaxf(lmax, fabsf(gl));
        }
      }
    }
  }
  if constexpr (MODE == 2) {
    #pragma unroll
    for (int o = 32; o; o >>= 1) lmax = fmaxf(lmax, __shfl_xor(lmax, o));
    __shared__ float red[4];
    if (lane == 0) red[wid] = lmax;
    __syncthreads();
    if (t == 0) atomicMaxF(a.slot, fmaxf(fmaxf(red[0], red[1]), fmaxf(red[2], red[3])));
  }
}

// ---------- fused attention (flash-style), fp32 out + absmax ----------
// 4 waves x 16 q-rows; KV tile = 128; V^T read direct from global (pre-transposed);
// per-wave P staging in LDS (XOR-swizzled), NO barriers in the main loop.
__global__ __launch_bounds__(256) void k_attn(const bf16* __restrict__ qb, const bf16* __restrict__ kb,
                                              const bf16* __restrict__ vt, const float* __restrict__ mask,
                                              float* __restrict__ out, float* __restrict__ slot) {
  constexpr int PE = 136;  // P row stride in elems (128 + 8)
  __shared__ __align__(16) bf16 Ps[4][16 * PE];
  __shared__ float red[4];
  const int t = threadIdx.x, wid = t >> 6, lane = t & 63;
  const int grp = lane >> 4, l15 = lane & 15;
  const int qt = blockIdx.x, bh = blockIdx.y;
  const int b = bh >> 4, h = bh & 15;                // H = 16
  const size_t qkbase = ((size_t)b * S_) * D_ + (size_t)h * HD_;
  const size_t vtbase = (size_t)b * D_ * S_ + (size_t)h * HD_ * S_;
  const int q0 = qt * 64 + wid * 16;
  bf16* __restrict__ myPs = Ps[wid];
  const int swzW = ((grp >> 1) & 1) << 4;            // write rows grp*4+i: bit3 = grp>>1
  const int swzR = ((l15 >> 3) & 1) << 4;            // read row = l15

  bf16x8 qf[2];
  #pragma unroll
  for (int c = 0; c < 2; c++)
    qf[c] = *(const bf16x8*)(qb + qkbase + (size_t)(q0 + l15) * D_ + c * 32 + grp * 8);

  const f32x4 zero = {0.f, 0.f, 0.f, 0.f};
  f32x4 ao[4];
  #pragma unroll
  for (int nf = 0; nf < 4; nf++) ao[nf] = zero;
  float mi[4], li[4];
  #pragma unroll
  for (int i = 0; i < 4; i++) { mi[i] = -INFINITY; li[i] = 0.f; }

  for (int kt0 = 0; kt0 < S_; kt0 += 128) {
    // QK^T : 16x128 scores per wave
    f32x4 accs[8];
    float madd[8];
    #pragma unroll
    for (int nf = 0; nf < 8; nf++) {
      const bf16* kp = kb + qkbase + (size_t)(kt0 + nf * 16 + l15) * D_ + grp * 8;
      const bf16x8 k0f = *(const bf16x8*)kp;
      const bf16x8 k1f = *(const bf16x8*)(kp + 32);
      f32x4 z = zero;
      z = mfma16(qf[0], k0f, z);
      z = mfma16(qf[1], k1f, z);
      accs[nf] = z;
      madd[nf] = (1.0f - mask[(size_t)b * S_ + kt0 + nf * 16 + l15]) * -10000.0f;
    }
    // online softmax; rows live across 16 lanes (l15), 4 rows/lane (i)
    float corr[4];
    #pragma unroll
    for (int i = 0; i < 4; i++) {
      float sc[8];
      #pragma unroll
      for (int nf = 0; nf < 8; nf++) sc[nf] = accs[nf][i] * 0.125f + madd[nf];
      float mx = sc[0];
      #pragma unroll
      for (int nf = 1; nf < 8; nf++) mx = fmaxf(mx, sc[nf]);
      mx = fmaxf(mx, __shfl_xor(mx, 1));
      mx = fmaxf(mx, __shfl_xor(mx, 2));
      mx = fmaxf(mx, __shfl_xor(mx, 4));
      mx = fmaxf(mx, __shfl_xor(mx, 8));
      const float mnew = fmaxf(mi[i], mx);
      corr[i] = __expf(mi[i] - mnew);
      float rs = 0.f;
      const int rowbase = (grp * 4 + i) * PE;
      #pragma unroll
      for (int nf = 0; nf < 8; nf++) {
        const float pv = __expf(sc[nf] - mnew);
        rs += pv;
        myPs[rowbase + ((nf * 16 + l15) ^ swzW)] = (bf16)pv;
      }
      rs += __shfl_xor(rs, 1); rs += __shfl_xor(rs, 2);
      rs += __shfl_xor(rs, 4); rs += __shfl_xor(rs, 8);
      li[i] = li[i] * corr[i] + rs;
      mi[i] = mnew;
    }
    #pragma unroll
    for (int nf = 0; nf < 4; nf++) {
      f32x4 aa = ao[nf];
      aa[0] *= corr[0]; aa[1] *= corr[1]; aa[2] *= corr[2]; aa[3] *= corr[3];
      ao[nf] = aa;
    }
    // P @ V : A = P rows from per-wave LDS, B = V^T rows from global
    #pragma unroll
    for (int c = 0; c < 4; c++) {
      const bf16x8 pa = *(const bf16x8*)(myPs + l15 * PE + ((c * 32 + grp * 8) ^ swzR));
      #pragma unroll
      for (int nf = 0; nf < 4; nf++) {
        const bf16x8 bv = *(const bf16x8*)(vt + vtbase + (size_t)(nf * 16 + l15) * S_ +
                                           kt0 + c * 32 + grp * 8);
        ao[nf] = mfma16(pa, bv, ao[nf]);
      }
    }
  }
  // epilogue: normalize, write fp32, absmax
  float inv[4];
  #pragma unroll
  for (int i = 0; i < 4; i++) inv[i] = 1.0f / li[i];
  float lmax = 0.f;
  #pragma unroll
  for (int nf = 0; nf < 4; nf++) {
    #pragma unroll
    for (int i = 0; i < 4; i++) {
      const float o = ao[nf][i] * inv[i];
      out[qkbase + (size_t)(q0 + grp * 4 + i) * D_ + nf * 16 + l15] = o;
      lmax = fmaxf(lmax, fabsf(o));
    }
  }
  #pragma unroll
  for (int o = 32; o; o >>= 1) lmax = fmaxf(lmax, __shfl_xor(lmax, o));
  if (lane == 0) red[wid] = lmax;
  __syncthreads();
  if (t == 0) atomicMaxF(slot, fmaxf(fmaxf(red[0], red[1]), fmaxf(red[2], red[3])));
}

// ---------- launch ----------
extern "C" void kernel_launch(void* const* d_in, const int* in_sizes, int n_in,
                              void* d_out, int out_size, void* d_ws, size_t ws_size,
                              hipStream_t stream) {
  const float* hs   = (const float*)d_in[0];
  const float* mask = (const float*)d_in[1];
  const float* wq = (const float*)d_in[2];  const float* bq = (const float*)d_in[3];
  const float* wk = (const float*)d_in[4];  const float* bk = (const float*)d_in[5];
  const float* wv = (const float*)d_in[6];  const float* bv = (const float*)d_in[7];
  const float* wo = (const float*)d_in[8];  const float* bo = (const float*)d_in[9];
  const float* w1 = (const float*)d_in[10]; const float* b1 = (const float*)d_in[11];
  const float* w2 = (const float*)d_in[12]; const float* b2 = (const float*)d_in[13];
  const float* g1 = (const float*)d_in[14]; const float* be1 = (const float*)d_in[15];
  const float* g2 = (const float*)d_in[16]; const float* be2 = (const float*)d_in[17];
  const int* wbits = (const int*)d_in[18];
  const int* abits = (const int*)d_in[19];

  // workspace layout (bytes)
  char* ws = (char*)d_ws;
  size_t off = 0;
  float* scal = (float*)ws;                      off += 256;        // absmax slots
  float* fbuf = (float*)(ws + off);              off += (size_t)NT * D_ * 4;  // x1f/attnf/x2f
  bf16*  qx   = (bf16*)(ws + off);               off += (size_t)NT * D_ * 2;  // x1q/attnq/x2q
  bf16*  qb   = (bf16*)(ws + off);               off += (size_t)NT * D_ * 2;
  bf16*  kbuf = (bf16*)(ws + off);               off += (size_t)NT * D_ * 2;
  bf16*  vbuf = (bf16*)(ws + off);               off += (size_t)NT * D_ * 2;  // holds V^T
  float* h2   = (float*)(ws + off);              off += (size_t)NT * D_ * 4;  // attn residual out
  bf16*  h1   = (bf16*)(ws + off);               off += (size_t)NT * I_ * 2;  // gelu out (quant ip)
  bf16*  wqq  = (bf16*)(ws + off);               off += (size_t)D_ * D_ * 2;
  bf16*  wkq  = (bf16*)(ws + off);               off += (size_t)D_ * D_ * 2;
  bf16*  wvq  = (bf16*)(ws + off);               off += (size_t)D_ * D_ * 2;
  bf16*  woq  = (bf16*)(ws + off);               off += (size_t)D_ * D_ * 2;
  bf16*  w1q  = (bf16*)(ws + off);               off += (size_t)I_ * D_ * 2;
  bf16*  w2q  = (bf16*)(ws + off);               off += (size_t)D_ * I_ * 2;
  if (ws_size < off) return;  // insufficient workspace: fail cleanly

  // slots: 0 x1, 1 attn, 2 x2, 3 h1, 4..9 weights
  k_init<<<1, 64, 0, stream>>>(scal);

  const size_t nDD4 = (size_t)D_ * D_ / 4, nDI4 = (size_t)D_ * I_ / 4;
  WArgs wa;
  wa.w[0] = wq; wa.w[1] = wk; wa.w[2] = wv; wa.w[3] = wo; wa.w[4] = w1; wa.w[5] = w2;
  wa.q[0] = wqq; wa.q[1] = wkq; wa.q[2] = wvq; wa.q[3] = woq; wa.q[4] = w1q; wa.q[5] = w2q;
  wa.n4[0] = nDD4; wa.n4[1] = nDD4; wa.n4[2] = nDD4; wa.n4[3] = nDD4;
  wa.n4[4] = nDI4; wa.n4[5] = nDI4;
  k_absmax6<<<dim3(1024, 1, 6), 256, 0, stream>>>(wa, scal + 4);
  k_quant6<<<dim3(1024, 1, 6), 256, 0, stream>>>(wa, scal + 4, wbits);

  const size_t nND4 = (size_t)NT * D_ / 4;

  // LN1 -> fake-quant -> fused QKV GEMM (V written transposed)
  k_ln<<<NT, 256, 0, stream>>>(hs, g1, be1, fbuf, scal + 0);
  k_quant<<<2048, 256, 0, stream>>>(fbuf, qx, scal + 0, abits, nND4);
  {
    GemmArgs ga{};
    ga.A = qx; ga.B0 = wqq; ga.B1 = wkq; ga.B2 = wvq;
    ga.bias0 = bq; ga.bias1 = bk; ga.bias2 = bv;
    ga.out0 = qb; ga.out1 = kbuf; ga.out2 = vbuf;
    ga.K = D_; ga.ldc = D_;
    k_gemm<0><<<dim3(NT / 128, D_ / 128, 3), 256, 0, stream>>>(ga);
  }

  // attention -> fake-quant -> out-proj (+residual)
  k_attn<<<dim3(S_ / 64, B_ * H_), 256, 0, stream>>>(qb, kbuf, vbuf, mask, fbuf, scal + 1);
  k_quant<<<2048, 256, 0, stream>>>(fbuf, qx, scal + 1, abits, nND4);
  {
    GemmArgs ga{};
    ga.A = qx; ga.B0 = woq; ga.bias0 = bo; ga.out0 = h2; ga.res = hs;
    ga.K = D_; ga.ldc = D_;
    k_gemm<1><<<dim3(NT / 128, D_ / 128), 256, 0, stream>>>(ga);
  }

  // LN2 -> fake-quant -> MLP1 (gelu + absmax) -> fake-quant -> MLP2 (+residual)
  k_ln<<<NT, 256, 0, stream>>>(h2, g2, be2, fbuf, scal + 2);
  k_quant<<<2048, 256, 0, stream>>>(fbuf, qx, scal + 2, abits, nND4);
  {
    GemmArgs ga{};
    ga.A = qx; ga.B0 = w1q; ga.bias0 = b1; ga.out0 = h1; ga.slot = scal + 3;
    ga.K = D_; ga.ldc = I_;
    k_gemm<2><<<dim3(NT / 128, I_ / 128), 256, 0, stream>>>(ga);
  }
  k_quant_ip<<<(NT * (size_t)I_ / 8 + 255) / 256, 256, 0, stream>>>(h1, scal + 3, abits,
                                                                    (size_t)NT * I_ / 8);
  {
    GemmArgs ga{};
    ga.A = h1; ga.B0 = w2q; ga.bias0 = b2; ga.out0 = d_out; ga.res = h2;
    ga.K = I_; ga.ldc = D_;
    k_gemm<1><<<dim3(NT / 128, D_ / 128), 256, 0, stream>>>(ga);
  }
}

// Round 3
// 593.642 us; speedup vs baseline: 1.3376x; 1.3376x over previous
//
#include <hip/hip_runtime.h>
#include <hip/hip_bf16.h>
#include <math.h>

typedef __bf16 bf16;
typedef __bf16 bf16x8 __attribute__((ext_vector_type(8)));
typedef __bf16 bf16x4 __attribute__((ext_vector_type(4)));
typedef float  f32x4  __attribute__((ext_vector_type(4)));

static constexpr int B_  = 2;
static constexpr int S_  = 2048;
static constexpr int D_  = 1024;
static constexpr int H_  = 16;
static constexpr int HD_ = 64;
static constexpr int I_  = 4096;
static constexpr int NT  = B_ * S_;       // 4096 tokens

// ---------- helpers ----------
__device__ __forceinline__ void atomicMaxF(float* p, float v) {
  // v >= 0 always (absmax), so uint bit-order == float order
  atomicMax((unsigned int*)p, __float_as_uint(v));
}

__device__ __forceinline__ f32x4 mfma16(bf16x8 a, bf16x8 b, f32x4 c) {
  return __builtin_amdgcn_mfma_f32_16x16x32_bf16(a, b, c, 0, 0, 0);
}

__device__ __forceinline__ void gload16(const void* g, void* lds) {
  // async global->LDS, 16B/lane; LDS dest = wave-uniform base + lane*16
  __builtin_amdgcn_global_load_lds(
      (const __attribute__((address_space(1))) void*)g,
      (__attribute__((address_space(3))) void*)lds, 16, 0, 0);
}

__device__ __forceinline__ float quant1(float x, float scale, float qmax) {
  // matches jnp: round(clip(x/scale,-qmax,qmax))*scale, RNE rounding
  return rintf(fminf(fmaxf(x / scale, -qmax), qmax)) * scale;
}

// max-reduce across the 16-lane group (DPP row_ror — VALU pipe, not LDS)
__device__ __forceinline__ float rowmax16(float x) {
  x = fmaxf(x, __int_as_float(__builtin_amdgcn_update_dpp(
                   __float_as_int(x), __float_as_int(x), 0x121, 0xf, 0xf, false)));
  x = fmaxf(x, __int_as_float(__builtin_amdgcn_update_dpp(
                   __float_as_int(x), __float_as_int(x), 0x122, 0xf, 0xf, false)));
  x = fmaxf(x, __int_as_float(__builtin_amdgcn_update_dpp(
                   __float_as_int(x), __float_as_int(x), 0x124, 0xf, 0xf, false)));
  x = fmaxf(x, __int_as_float(__builtin_amdgcn_update_dpp(
                   __float_as_int(x), __float_as_int(x), 0x128, 0xf, 0xf, false)));
  return x;
}

// stage a 64x64 bf16 tile into LDS, XOR-swizzle (chunk ^= row&7) applied on the
// GLOBAL source so the LDS dest stays linear (global_load_lds requirement).
__device__ __forceinline__ void stage64(const bf16* __restrict__ g, int rs, bf16* lds, int tt) {
  #pragma unroll
  for (int r = 0; r < 2; r++) {
    const int cl  = r * 256 + tt;          // 16B-chunk id in tile (512 total)
    const int row = cl >> 3;               // 8 chunks per 128B row
    const int scr = (cl & 7) ^ (row & 7);  // pre-swizzled source chunk
    gload16(g + (size_t)row * rs + scr * 8,
            (char*)lds + (size_t)(r * 256 + (tt & 192)) * 16);
  }
}

// ---------- scalar init ----------
__global__ void k_init(float* s) {
  if (threadIdx.x < 32) s[threadIdx.x] = 0.f;
}

// ---------- fused per-tensor absmax + quant for the 6 weights ----------
struct WArgs {
  const float* w[6];
  bf16* q[6];
  size_t n4[6];
};

__global__ __launch_bounds__(256) void k_absmax6(WArgs a, float* __restrict__ slots) {
  const int z = blockIdx.z;
  const float* __restrict__ x = a.w[z];
  const size_t n4 = a.n4[z];
  size_t i = (size_t)blockIdx.x * 256 + threadIdx.x;
  const size_t stride = (size_t)gridDim.x * 256;
  float m = 0.f;
  for (; i < n4; i += stride) {
    float4 v = ((const float4*)x)[i];
    m = fmaxf(m, fmaxf(fmaxf(fabsf(v.x), fabsf(v.y)), fmaxf(fabsf(v.z), fabsf(v.w))));
  }
  #pragma unroll
  for (int o = 32; o; o >>= 1) m = fmaxf(m, __shfl_xor(m, o));
  __shared__ float red[4];
  if ((threadIdx.x & 63) == 0) red[threadIdx.x >> 6] = m;
  __syncthreads();
  if (threadIdx.x == 0)
    atomicMaxF(slots + z, fmaxf(fmaxf(red[0], red[1]), fmaxf(red[2], red[3])));
}

__global__ __launch_bounds__(256) void k_quant6(WArgs a, const float* __restrict__ slots,
                                                const int* __restrict__ bits) {
  const int z = blockIdx.z;
  const float* __restrict__ x = a.w[z];
  bf16* __restrict__ y = a.q[z];
  const size_t n4 = a.n4[z];
  const float qmax  = (float)((1 << (*bits - 1)) - 1);
  const float scale = fmaxf(slots[z], 1e-8f) / qmax;
  size_t i = (size_t)blockIdx.x * 256 + threadIdx.x;
  const size_t stride = (size_t)gridDim.x * 256;
  for (; i < n4; i += stride) {
    float4 v = ((const float4*)x)[i];
    bf16x4 o;
    o[0] = (bf16)quant1(v.x, scale, qmax);
    o[1] = (bf16)quant1(v.y, scale, qmax);
    o[2] = (bf16)quant1(v.z, scale, qmax);
    o[3] = (bf16)quant1(v.w, scale, qmax);
    ((bf16x4*)y)[i] = o;
  }
}

// ---------- fake-quant fp32 -> bf16 (activations) ----------
__global__ __launch_bounds__(256) void k_quant(const float* __restrict__ x, bf16* __restrict__ y,
                                               const float* __restrict__ slot,
                                               const int* __restrict__ bits, size_t n4) {
  const float qmax  = (float)((1 << (*bits - 1)) - 1);
  const float scale = fmaxf(*slot, 1e-8f) / qmax;
  size_t i = (size_t)blockIdx.x * 256 + threadIdx.x;
  const size_t stride = (size_t)gridDim.x * 256;
  for (; i < n4; i += stride) {
    float4 v = ((const float4*)x)[i];
    bf16x4 o;
    o[0] = (bf16)quant1(v.x, scale, qmax);
    o[1] = (bf16)quant1(v.y, scale, qmax);
    o[2] = (bf16)quant1(v.z, scale, qmax);
    o[3] = (bf16)quant1(v.w, scale, qmax);
    ((bf16x4*)y)[i] = o;
  }
}

// ---------- fake-quant bf16 in-place (GELU output) ----------
__global__ __launch_bounds__(256) void k_quant_ip(bf16* __restrict__ x,
                                                  const float* __restrict__ slot,
                                                  const int* __restrict__ bits, size_t n8) {
  const float qmax  = (float)((1 << (*bits - 1)) - 1);
  const float scale = fmaxf(*slot, 1e-8f) / qmax;
  size_t i = (size_t)blockIdx.x * 256 + threadIdx.x;
  if (i >= n8) return;
  bf16x8 v = ((const bf16x8*)x)[i];
  #pragma unroll
  for (int j = 0; j < 8; j++) v[j] = (bf16)quant1((float)v[j], scale, qmax);
  ((bf16x8*)x)[i] = v;
}

// ---------- LayerNorm (fp32 out, + absmax) : one block per row ----------
__global__ __launch_bounds__(256) void k_ln(const float* __restrict__ x, const float* __restrict__ g,
                                            const float* __restrict__ be, float* __restrict__ y,
                                            float* __restrict__ slot) {
  const int row = blockIdx.x, t = threadIdx.x;
  const float4 v = ((const float4*)(x + (size_t)row * D_))[t];
  float s = v.x + v.y + v.z + v.w;
  float q = v.x * v.x + v.y * v.y + v.z * v.z + v.w * v.w;
  #pragma unroll
  for (int o = 32; o; o >>= 1) { s += __shfl_xor(s, o); q += __shfl_xor(q, o); }
  __shared__ float red[8];
  const int wid = t >> 6;
  if ((t & 63) == 0) { red[wid] = s; red[4 + wid] = q; }
  __syncthreads();
  s = red[0] + red[1] + red[2] + red[3];
  q = red[4] + red[5] + red[6] + red[7];
  const float mean = s * (1.f / D_);
  const float rstd = rsqrtf(q * (1.f / D_) - mean * mean + 1e-5f);
  const float4 gv = ((const float4*)g)[t];
  const float4 bv = ((const float4*)be)[t];
  float4 o;
  o.x = (v.x - mean) * rstd * gv.x + bv.x;
  o.y = (v.y - mean) * rstd * gv.y + bv.y;
  o.z = (v.z - mean) * rstd * gv.z + bv.z;
  o.w = (v.w - mean) * rstd * gv.w + bv.w;
  ((float4*)(y + (size_t)row * D_))[t] = o;
  float m = fmaxf(fmaxf(fabsf(o.x), fabsf(o.y)), fmaxf(fabsf(o.z), fabsf(o.w)));
  #pragma unroll
  for (int oo = 32; oo; oo >>= 1) m = fmaxf(m, __shfl_xor(m, oo));
  __syncthreads();                 // red reuse
  if ((t & 63) == 0) red[wid] = m;
  __syncthreads();
  if (t == 0) atomicMaxF(slot, fmaxf(fmaxf(red[0], red[1]), fmaxf(red[2], red[3])));
}

// ---------- GEMM: C[M,N] = A[M,K] @ B[N,K]^T (+bias, +mode epilogue) ----------
// 128x128 tile, BK=32, 4 waves in 2x2, each wave 64x64 = 4x4 mfma_16x16x32 frags.
struct GemmArgs {
  const bf16* A;
  const bf16* B0; const bf16* B1; const bf16* B2;
  const float* bias0; const float* bias1; const float* bias2;
  void* out0; void* out1; void* out2;
  const float* res;   // MODE 1: residual (fp32, same layout as out)
  float* slot;        // MODE 2: absmax slot
  int K; int ldc;
};

// MODE 0: bf16 out (+bias), 3-way select by blockIdx.z (QKV fused);
//         z==2 (V) stores TRANSPOSED: [b][col][s] for attention's PV B-operand
// MODE 1: f32 out = acc + bias + res
// MODE 2: bf16 out = gelu(acc+bias), absmax -> slot
template <int MODE>
__global__ __launch_bounds__(256) void k_gemm(GemmArgs a) {
  __shared__ __align__(16) bf16 As[128 * 32];
  __shared__ __align__(16) bf16 Bs[128 * 32];
  const int t = threadIdx.x, wid = t >> 6, lane = t & 63;
  const int grp = lane >> 4, l15 = lane & 15;
  const int wm = wid >> 1, wn = wid & 1;
  const size_t m0 = (size_t)blockIdx.x * 128, n0 = (size_t)blockIdx.y * 128;
  const int K = a.K, ldc = a.ldc;

  const bf16* Bw; const float* bias; void* outv;
  if constexpr (MODE == 0) {
    const int z = blockIdx.z;
    Bw   = z == 0 ? a.B0 : (z == 1 ? a.B1 : a.B2);
    bias = z == 0 ? a.bias0 : (z == 1 ? a.bias1 : a.bias2);
    outv = z == 0 ? a.out0 : (z == 1 ? a.out1 : a.out2);
  } else {
    Bw = a.B0; bias = a.bias0; outv = a.out0;
  }

  const f32x4 zero = {0.f, 0.f, 0.f, 0.f};
  f32x4 acc[4][4];
  #pragma unroll
  for (int m = 0; m < 4; m++)
    #pragma unroll
    for (int n = 0; n < 4; n++) acc[m][n] = zero;

  for (int kt = 0; kt < K; kt += 32) {
    // stage A,B tiles (8KB each): 4 waves x 2 rounds x 1KB
    #pragma unroll
    for (int r = 0; r < 2; r++) {
      const int ob  = (wid * 2 + r) * 1024 + lane * 16;  // byte in tile
      const int row = ob >> 6;                            // 64B per row (32 bf16)
      const int col = (ob & 63) >> 1;
      gload16(a.A + (m0 + row) * (size_t)K + (kt + col), (char*)As + (size_t)(wid * 2 + r) * 1024);
      gload16(Bw  + (n0 + row) * (size_t)K + (kt + col), (char*)Bs + (size_t)(wid * 2 + r) * 1024);
    }
    __syncthreads();   // drains vmcnt (global_load_lds) + lgkm
    bf16x8 af[4], bfv[4];
    #pragma unroll
    for (int m = 0; m < 4; m++)
      af[m] = *(const bf16x8*)(As + (wm * 64 + m * 16 + l15) * 32 + grp * 8);
    #pragma unroll
    for (int n = 0; n < 4; n++)
      bfv[n] = *(const bf16x8*)(Bs + (wn * 64 + n * 16 + l15) * 32 + grp * 8);
    #pragma unroll
    for (int m = 0; m < 4; m++)
      #pragma unroll
      for (int n = 0; n < 4; n++)
        acc[m][n] = mfma16(af[m], bfv[n], acc[m][n]);
    __syncthreads();   // protect LDS before next stage
  }

  // epilogue: C/D frag layout: row=(lane>>4)*4+i, col=lane&15
  const size_t gr0 = m0 + wm * 64 + grp * 4;
  const size_t gc0 = n0 + wn * 64 + l15;

  if constexpr (MODE == 0) {
    if (blockIdx.z == 2) {
      // V^T store: out[b][gc][s] packed bf16x4 along s (i dimension)
      #pragma unroll
      for (int n = 0; n < 4; n++) {
        const size_t gc = gc0 + n * 16;
        const float bc = bias[gc];
        #pragma unroll
        for (int m = 0; m < 4; m++) {
          const size_t gr = gr0 + m * 16;              // tokens gr..gr+3, same batch
          const size_t bb = gr >> 11, s0 = gr & (S_ - 1);
          bf16x4 vv;
          #pragma unroll
          for (int i = 0; i < 4; i++) vv[i] = (bf16)(acc[m][n][i] + bc);
          *(bf16x4*)((bf16*)outv + bb * (size_t)D_ * S_ + gc * S_ + s0) = vv;
        }
      }
      return;
    }
  }

  float lmax = 0.f;
  #pragma unroll
  for (int n = 0; n < 4; n++) {
    const size_t gc = gc0 + n * 16;
    const float bc = bias[gc];
    #pragma unroll
    for (int m = 0; m < 4; m++) {
      const size_t gr = gr0 + m * 16;
      #pragma unroll
      for (int i = 0; i < 4; i++) {
        const float v = acc[m][n][i] + bc;
        const size_t idx = (gr + i) * (size_t)ldc + gc;
        if constexpr (MODE == 0) {
          ((bf16*)outv)[idx] = (bf16)v;
        } else if constexpr (MODE == 1) {
          ((float*)outv)[idx] = v + a.res[idx];
        } else {
          const float gl = 0.5f * v * (1.0f + erff(v * 0.7071067811865475f));
          ((bf16*)outv)[idx] = (bf16)gl;
          lmax = fmaxf(lmax, fabsf(gl));
        }
      }
    }
  }
  if constexpr (MODE == 2) {
    #pragma unroll
    for (int o = 32; o; o >>= 1) lmax = fmaxf(lmax, __shfl_xor(lmax, o));
    __shared__ float red[4];
    if (lane == 0) red[wid] = lmax;
    __syncthreads();
    if (t == 0) atomicMaxF(a.slot, fmaxf(fmaxf(red[0], red[1]), fmaxf(red[2], red[3])));
  }
}

// ---------- fused attention (flash-style), fp32 out + absmax ----------
// 4 waves x 32 q-rows = 128 q/block; KV tile = 64, K and V^T staged in LDS via
// global_load_lds (source-preswizzled T2), double-buffered, ONE barrier/tile.
__global__ __launch_bounds__(256) void k_attn(const bf16* __restrict__ qb, const bf16* __restrict__ kb,
                                              const bf16* __restrict__ vt, const float* __restrict__ mask,
                                              float* __restrict__ out, float* __restrict__ slot) {
  constexpr int PE = 72;                    // P row stride (64 + 8), 144B = 9*16B
  constexpr float SCL2 = 0.18033688f;       // 0.125 * log2(e)   (exp2 domain)
  constexpr float MSK2 = -14426.9504f;      // -10000 * log2(e)
  __shared__ __align__(16) bf16 Ks[2][64 * 64];   // [buf][key][d]  (chunk-swizzled)
  __shared__ __align__(16) bf16 Vs[2][64 * 64];   // [buf][d][key]  (chunk-swizzled)
  __shared__ __align__(16) bf16 Ps[4][32 * PE];   // per-wave P
  __shared__ float red[4];
  const int t = threadIdx.x, wid = t >> 6, lane = t & 63;
  const int grp = lane >> 4, l15 = lane & 15;
  const int b = blockIdx.y >> 4, h = blockIdx.y & 15;   // H = 16
  const size_t qkbase = ((size_t)b * S_) * D_ + (size_t)h * HD_;
  const size_t vtbase = (size_t)b * D_ * S_ + (size_t)h * HD_ * S_;
  const int q0 = blockIdx.x * 128 + wid * 32;
  bf16* __restrict__ myPs = Ps[wid];
  const int swzW = ((grp >> 1) & 1) << 4;   // P write: XOR col bit4 with row bit3
  const int swzR = ((l15 >> 3) & 1) << 4;   // P read:  row = l15

  bf16x8 qf[2][2];
  #pragma unroll
  for (int qi = 0; qi < 2; qi++)
    #pragma unroll
    for (int c = 0; c < 2; c++)
      qf[qi][c] = *(const bf16x8*)(qb + qkbase + (size_t)(q0 + qi * 16 + l15) * D_ +
                                   c * 32 + grp * 8);

  const f32x4 zero = {0.f, 0.f, 0.f, 0.f};
  f32x4 ao[2][4];
  float mi[2][4], li[2][4];
  #pragma unroll
  for (int qi = 0; qi < 2; qi++)
    #pragma unroll
    for (int i = 0; i < 4; i++) { ao[qi][i] = zero; mi[qi][i] = -INFINITY; li[qi][i] = 0.f; }

  // prologue: stage tile 0
  stage64(kb + qkbase, D_, Ks[0], t);
  stage64(vt + vtbase, S_, Vs[0], t);
  __syncthreads();
  int cur = 0;

  for (int kt0 = 0; kt0 < S_; kt0 += 64) {
    // prefetch next tile (overlaps with compute, drained by tile-end barrier)
    if (kt0 + 64 < S_) {
      stage64(kb + qkbase + (size_t)(kt0 + 64) * D_, D_, Ks[cur ^ 1], t);
      stage64(vt + vtbase + (kt0 + 64), S_, Vs[cur ^ 1], t);
    }
    float madd[4];
    #pragma unroll
    for (int nf = 0; nf < 4; nf++)
      madd[nf] = (1.0f - mask[(size_t)b * S_ + kt0 + nf * 16 + l15]) * MSK2;

    // QK^T: 2 q-frags x 64 keys (K frag shared across q-frags)
    f32x4 accs[2][4];
    #pragma unroll
    for (int qi = 0; qi < 2; qi++)
      #pragma unroll
      for (int nf = 0; nf < 4; nf++) accs[qi][nf] = zero;
    #pragma unroll
    for (int nf = 0; nf < 4; nf++) {
      const int row = nf * 16 + l15;
      #pragma unroll
      for (int c = 0; c < 2; c++) {
        const int ch = (c * 4 + grp) ^ (l15 & 7);
        const bf16x8 kf = *(const bf16x8*)(&Ks[cur][row * 64 + ch * 8]);
        accs[0][nf] = mfma16(qf[0][c], kf, accs[0][nf]);
        accs[1][nf] = mfma16(qf[1][c], kf, accs[1][nf]);
      }
    }

    // online softmax (exp2 domain); li kept lane-partial (reduced in epilogue)
    float corr[2][4];
    #pragma unroll
    for (int qi = 0; qi < 2; qi++) {
      #pragma unroll
      for (int i = 0; i < 4; i++) {
        const float sc0 = accs[qi][0][i] * SCL2 + madd[0];
        const float sc1 = accs[qi][1][i] * SCL2 + madd[1];
        const float sc2 = accs[qi][2][i] * SCL2 + madd[2];
        const float sc3 = accs[qi][3][i] * SCL2 + madd[3];
        float mx = fmaxf(fmaxf(sc0, sc1), fmaxf(sc2, sc3));
        mx = rowmax16(mx);
        const float mnew = fmaxf(mi[qi][i], mx);
        const float co = exp2f(mi[qi][i] - mnew);
        corr[qi][i] = co;
        mi[qi][i] = mnew;
        const float p0 = exp2f(sc0 - mnew);
        const float p1 = exp2f(sc1 - mnew);
        const float p2 = exp2f(sc2 - mnew);
        const float p3 = exp2f(sc3 - mnew);
        li[qi][i] = li[qi][i] * co + ((p0 + p1) + (p2 + p3));
        const int rb = (qi * 16 + grp * 4 + i) * PE;
        myPs[rb + ((l15) ^ swzW)]      = (bf16)p0;
        myPs[rb + ((16 + l15) ^ swzW)] = (bf16)p1;
        myPs[rb + ((32 + l15) ^ swzW)] = (bf16)p2;
        myPs[rb + ((48 + l15) ^ swzW)] = (bf16)p3;
      }
    }
    #pragma unroll
    for (int qi = 0; qi < 2; qi++)
      #pragma unroll
      for (int nf = 0; nf < 4; nf++) {
        f32x4 aa = ao[qi][nf];
        aa[0] *= corr[qi][0]; aa[1] *= corr[qi][1];
        aa[2] *= corr[qi][2]; aa[3] *= corr[qi][3];
        ao[qi][nf] = aa;
      }

    // P @ V (V^T frag shared across q-frags)
    #pragma unroll
    for (int c = 0; c < 2; c++) {
      const int pc = (c * 32 + grp * 8) ^ swzR;
      const bf16x8 pa0 = *(const bf16x8*)(myPs + l15 * PE + pc);
      const bf16x8 pa1 = *(const bf16x8*)(myPs + (16 + l15) * PE + pc);
      #pragma unroll
      for (int nf = 0; nf < 4; nf++) {
        const int row = nf * 16 + l15;
        const int ch = (c * 4 + grp) ^ (l15 & 7);
        const bf16x8 bv = *(const bf16x8*)(&Vs[cur][row * 64 + ch * 8]);
        ao[0][nf] = mfma16(pa0, bv, ao[0][nf]);
        ao[1][nf] = mfma16(pa1, bv, ao[1][nf]);
      }
    }
    __syncthreads();   // next tile staged + LDS reuse safe
    cur ^= 1;
  }

  // epilogue: reduce li across the 16-lane group once, normalize, write, absmax
  float lmax = 0.f;
  #pragma unroll
  for (int qi = 0; qi < 2; qi++) {
    #pragma unroll
    for (int i = 0; i < 4; i++) {
      float l = li[qi][i];
      l += __shfl_xor(l, 1); l += __shfl_xor(l, 2);
      l += __shfl_xor(l, 4); l += __shfl_xor(l, 8);
      const float invl = 1.0f / l;
      #pragma unroll
      for (int nf = 0; nf < 4; nf++) {
        const float o = ao[qi][nf][i] * invl;
        out[qkbase + (size_t)(q0 + qi * 16 + grp * 4 + i) * D_ + nf * 16 + l15] = o;
        lmax = fmaxf(lmax, fabsf(o));
      }
    }
  }
  #pragma unroll
  for (int o = 32; o; o >>= 1) lmax = fmaxf(lmax, __shfl_xor(lmax, o));
  if (lane == 0) red[wid] = lmax;
  __syncthreads();
  if (t == 0) atomicMaxF(slot, fmaxf(fmaxf(red[0], red[1]), fmaxf(red[2], red[3])));
}

// ---------- launch ----------
extern "C" void kernel_launch(void* const* d_in, const int* in_sizes, int n_in,
                              void* d_out, int out_size, void* d_ws, size_t ws_size,
                              hipStream_t stream) {
  const float* hs   = (const float*)d_in[0];
  const float* mask = (const float*)d_in[1];
  const float* wq = (const float*)d_in[2];  const float* bq = (const float*)d_in[3];
  const float* wk = (const float*)d_in[4];  const float* bk = (const float*)d_in[5];
  const float* wv = (const float*)d_in[6];  const float* bv = (const float*)d_in[7];
  const float* wo = (const float*)d_in[8];  const float* bo = (const float*)d_in[9];
  const float* w1 = (const float*)d_in[10]; const float* b1 = (const float*)d_in[11];
  const float* w2 = (const float*)d_in[12]; const float* b2 = (const float*)d_in[13];
  const float* g1 = (const float*)d_in[14]; const float* be1 = (const float*)d_in[15];
  const float* g2 = (const float*)d_in[16]; const float* be2 = (const float*)d_in[17];
  const int* wbits = (const int*)d_in[18];
  const int* abits = (const int*)d_in[19];

  // workspace layout (bytes)
  char* ws = (char*)d_ws;
  size_t off = 0;
  float* scal = (float*)ws;                      off += 256;        // absmax slots
  float* fbuf = (float*)(ws + off);              off += (size_t)NT * D_ * 4;  // x1f/attnf/x2f
  bf16*  qx   = (bf16*)(ws + off);               off += (size_t)NT * D_ * 2;  // x1q/attnq/x2q
  bf16*  qb   = (bf16*)(ws + off);               off += (size_t)NT * D_ * 2;
  bf16*  kbuf = (bf16*)(ws + off);               off += (size_t)NT * D_ * 2;
  bf16*  vbuf = (bf16*)(ws + off);               off += (size_t)NT * D_ * 2;  // holds V^T
  float* h2   = (float*)(ws + off);              off += (size_t)NT * D_ * 4;  // attn residual out
  bf16*  h1   = (bf16*)(ws + off);               off += (size_t)NT * I_ * 2;  // gelu out (quant ip)
  bf16*  wqq  = (bf16*)(ws + off);               off += (size_t)D_ * D_ * 2;
  bf16*  wkq  = (bf16*)(ws + off);               off += (size_t)D_ * D_ * 2;
  bf16*  wvq  = (bf16*)(ws + off);               off += (size_t)D_ * D_ * 2;
  bf16*  woq  = (bf16*)(ws + off);               off += (size_t)D_ * D_ * 2;
  bf16*  w1q  = (bf16*)(ws + off);               off += (size_t)I_ * D_ * 2;
  bf16*  w2q  = (bf16*)(ws + off);               off += (size_t)D_ * I_ * 2;
  if (ws_size < off) return;  // insufficient workspace: fail cleanly

  // slots: 0 x1, 1 attn, 2 x2, 3 h1, 4..9 weights
  k_init<<<1, 64, 0, stream>>>(scal);

  const size_t nDD4 = (size_t)D_ * D_ / 4, nDI4 = (size_t)D_ * I_ / 4;
  WArgs wa;
  wa.w[0] = wq; wa.w[1] = wk; wa.w[2] = wv; wa.w[3] = wo; wa.w[4] = w1; wa.w[5] = w2;
  wa.q[0] = wqq; wa.q[1] = wkq; wa.q[2] = wvq; wa.q[3] = woq; wa.q[4] = w1q; wa.q[5] = w2q;
  wa.n4[0] = nDD4; wa.n4[1] = nDD4; wa.n4[2] = nDD4; wa.n4[3] = nDD4;
  wa.n4[4] = nDI4; wa.n4[5] = nDI4;
  k_absmax6<<<dim3(1024, 1, 6), 256, 0, stream>>>(wa, scal + 4);
  k_quant6<<<dim3(1024, 1, 6), 256, 0, stream>>>(wa, scal + 4, wbits);

  const size_t nND4 = (size_t)NT * D_ / 4;

  // LN1 -> fake-quant -> fused QKV GEMM (V written transposed)
  k_ln<<<NT, 256, 0, stream>>>(hs, g1, be1, fbuf, scal + 0);
  k_quant<<<2048, 256, 0, stream>>>(fbuf, qx, scal + 0, abits, nND4);
  {
    GemmArgs ga{};
    ga.A = qx; ga.B0 = wqq; ga.B1 = wkq; ga.B2 = wvq;
    ga.bias0 = bq; ga.bias1 = bk; ga.bias2 = bv;
    ga.out0 = qb; ga.out1 = kbuf; ga.out2 = vbuf;
    ga.K = D_; ga.ldc = D_;
    k_gemm<0><<<dim3(NT / 128, D_ / 128, 3), 256, 0, stream>>>(ga);
  }

  // attention -> fake-quant -> out-proj (+residual)
  k_attn<<<dim3(S_ / 128, B_ * H_), 256, 0, stream>>>(qb, kbuf, vbuf, mask, fbuf, scal + 1);
  k_quant<<<2048, 256, 0, stream>>>(fbuf, qx, scal + 1, abits, nND4);
  {
    GemmArgs ga{};
    ga.A = qx; ga.B0 = woq; ga.bias0 = bo; ga.out0 = h2; ga.res = hs;
    ga.K = D_; ga.ldc = D_;
    k_gemm<1><<<dim3(NT / 128, D_ / 128), 256, 0, stream>>>(ga);
  }

  // LN2 -> fake-quant -> MLP1 (gelu + absmax) -> fake-quant -> MLP2 (+residual)
  k_ln<<<NT, 256, 0, stream>>>(h2, g2, be2, fbuf, scal + 2);
  k_quant<<<2048, 256, 0, stream>>>(fbuf, qx, scal + 2, abits, nND4);
  {
    GemmArgs ga{};
    ga.A = qx; ga.B0 = w1q; ga.bias0 = b1; ga.out0 = h1; ga.slot = scal + 3;
    ga.K = D_; ga.ldc = I_;
    k_gemm<2><<<dim3(NT / 128, I_ / 128), 256, 0, stream>>>(ga);
  }
  k_quant_ip<<<(NT * (size_t)I_ / 8 + 255) / 256, 256, 0, stream>>>(h1, scal + 3, abits,
                                                                    (size_t)NT * I_ / 8);
  {
    GemmArgs ga{};
    ga.A = h1; ga.B0 = w2q; ga.bias0 = b2; ga.out0 = d_out; ga.res = h2;
    ga.K = I_; ga.ldc = D_;
    k_gemm<1><<<dim3(NT / 128, D_ / 128), 256, 0, stream>>>(ga);
  }
}

// Round 4
// 560.917 us; speedup vs baseline: 1.4156x; 1.0583x over previous
//
#include <hip/hip_runtime.h>
#include <hip/hip_bf16.h>
#include <math.h>

typedef __bf16 bf16;
typedef __bf16 bf16x8 __attribute__((ext_vector_type(8)));
typedef __bf16 bf16x4 __attribute__((ext_vector_type(4)));
typedef float  f32x4  __attribute__((ext_vector_type(4)));

static constexpr int B_  = 2;
static constexpr int S_  = 2048;
static constexpr int D_  = 1024;
static constexpr int H_  = 16;
static constexpr int HD_ = 64;
static constexpr int I_  = 4096;
static constexpr int NT  = B_ * S_;       // 4096 tokens

// ---------- helpers ----------
__device__ __forceinline__ void atomicMaxF(float* p, float v) {
  // v >= 0 always (absmax), so uint bit-order == float order
  atomicMax((unsigned int*)p, __float_as_uint(v));
}

__device__ __forceinline__ f32x4 mfma16(bf16x8 a, bf16x8 b, f32x4 c) {
  return __builtin_amdgcn_mfma_f32_16x16x32_bf16(a, b, c, 0, 0, 0);
}

__device__ __forceinline__ void gload16(const void* g, void* lds) {
  // async global->LDS, 16B/lane; LDS dest = wave-uniform base + lane*16
  __builtin_amdgcn_global_load_lds(
      (const __attribute__((address_space(1))) void*)g,
      (__attribute__((address_space(3))) void*)lds, 16, 0, 0);
}

__device__ __forceinline__ float quant1(float x, float scale, float qmax) {
  // matches jnp: round(clip(x/scale,-qmax,qmax))*scale, RNE rounding
  return rintf(fminf(fmaxf(x / scale, -qmax), qmax)) * scale;
}

// max-reduce across the 16-lane group (DPP row_ror — VALU pipe, not LDS)
__device__ __forceinline__ float rowmax16(float x) {
  x = fmaxf(x, __int_as_float(__builtin_amdgcn_update_dpp(
                   __float_as_int(x), __float_as_int(x), 0x121, 0xf, 0xf, false)));
  x = fmaxf(x, __int_as_float(__builtin_amdgcn_update_dpp(
                   __float_as_int(x), __float_as_int(x), 0x122, 0xf, 0xf, false)));
  x = fmaxf(x, __int_as_float(__builtin_amdgcn_update_dpp(
                   __float_as_int(x), __float_as_int(x), 0x124, 0xf, 0xf, false)));
  x = fmaxf(x, __int_as_float(__builtin_amdgcn_update_dpp(
                   __float_as_int(x), __float_as_int(x), 0x128, 0xf, 0xf, false)));
  return x;
}

// stage a 64x64 bf16 tile into LDS, XOR-swizzle (chunk ^= row&7) applied on the
// GLOBAL source so the LDS dest stays linear (global_load_lds requirement).
__device__ __forceinline__ void stage64(const bf16* __restrict__ g, int rs, bf16* lds, int tt) {
  #pragma unroll
  for (int r = 0; r < 2; r++) {
    const int cl  = r * 256 + tt;          // 16B-chunk id in tile (512 total)
    const int row = cl >> 3;               // 8 chunks per 128B row
    const int scr = (cl & 7) ^ (row & 7);  // pre-swizzled source chunk
    gload16(g + (size_t)row * rs + scr * 8,
            (char*)lds + (size_t)(r * 256 + (tt & 192)) * 16);
  }
}

// ---------- scalar init ----------
__global__ void k_init(float* s) {
  if (threadIdx.x < 32) s[threadIdx.x] = 0.f;
}

// ---------- fused per-tensor absmax + quant for the 6 weights ----------
struct WArgs {
  const float* w[6];
  bf16* q[6];
  size_t n4[6];
};

__global__ __launch_bounds__(256) void k_absmax6(WArgs a, float* __restrict__ slots) {
  const int z = blockIdx.z;
  const float* __restrict__ x = a.w[z];
  const size_t n4 = a.n4[z];
  size_t i = (size_t)blockIdx.x * 256 + threadIdx.x;
  const size_t stride = (size_t)gridDim.x * 256;
  float m = 0.f;
  for (; i < n4; i += stride) {
    float4 v = ((const float4*)x)[i];
    m = fmaxf(m, fmaxf(fmaxf(fabsf(v.x), fabsf(v.y)), fmaxf(fabsf(v.z), fabsf(v.w))));
  }
  #pragma unroll
  for (int o = 32; o; o >>= 1) m = fmaxf(m, __shfl_xor(m, o));
  __shared__ float red[4];
  if ((threadIdx.x & 63) == 0) red[threadIdx.x >> 6] = m;
  __syncthreads();
  if (threadIdx.x == 0)
    atomicMaxF(slots + z, fmaxf(fmaxf(red[0], red[1]), fmaxf(red[2], red[3])));
}

__global__ __launch_bounds__(256) void k_quant6(WArgs a, const float* __restrict__ slots,
                                                const int* __restrict__ bits) {
  const int z = blockIdx.z;
  const float* __restrict__ x = a.w[z];
  bf16* __restrict__ y = a.q[z];
  const size_t n4 = a.n4[z];
  const float qmax  = (float)((1 << (*bits - 1)) - 1);
  const float scale = fmaxf(slots[z], 1e-8f) / qmax;
  size_t i = (size_t)blockIdx.x * 256 + threadIdx.x;
  const size_t stride = (size_t)gridDim.x * 256;
  for (; i < n4; i += stride) {
    float4 v = ((const float4*)x)[i];
    bf16x4 o;
    o[0] = (bf16)quant1(v.x, scale, qmax);
    o[1] = (bf16)quant1(v.y, scale, qmax);
    o[2] = (bf16)quant1(v.z, scale, qmax);
    o[3] = (bf16)quant1(v.w, scale, qmax);
    ((bf16x4*)y)[i] = o;
  }
}

// ---------- fake-quant fp32 -> bf16 (activations) ----------
__global__ __launch_bounds__(256) void k_quant(const float* __restrict__ x, bf16* __restrict__ y,
                                               const float* __restrict__ slot,
                                               const int* __restrict__ bits, size_t n4) {
  const float qmax  = (float)((1 << (*bits - 1)) - 1);
  const float scale = fmaxf(*slot, 1e-8f) / qmax;
  size_t i = (size_t)blockIdx.x * 256 + threadIdx.x;
  const size_t stride = (size_t)gridDim.x * 256;
  for (; i < n4; i += stride) {
    float4 v = ((const float4*)x)[i];
    bf16x4 o;
    o[0] = (bf16)quant1(v.x, scale, qmax);
    o[1] = (bf16)quant1(v.y, scale, qmax);
    o[2] = (bf16)quant1(v.z, scale, qmax);
    o[3] = (bf16)quant1(v.w, scale, qmax);
    ((bf16x4*)y)[i] = o;
  }
}

// ---------- fake-quant bf16 in-place (GELU output) ----------
__global__ __launch_bounds__(256) void k_quant_ip(bf16* __restrict__ x,
                                                  const float* __restrict__ slot,
                                                  const int* __restrict__ bits, size_t n8) {
  const float qmax  = (float)((1 << (*bits - 1)) - 1);
  const float scale = fmaxf(*slot, 1e-8f) / qmax;
  size_t i = (size_t)blockIdx.x * 256 + threadIdx.x;
  if (i >= n8) return;
  bf16x8 v = ((const bf16x8*)x)[i];
  #pragma unroll
  for (int j = 0; j < 8; j++) v[j] = (bf16)quant1((float)v[j], scale, qmax);
  ((bf16x8*)x)[i] = v;
}

// ---------- LayerNorm (fp32 out, + absmax) : one block per row ----------
__global__ __launch_bounds__(256) void k_ln(const float* __restrict__ x, const float* __restrict__ g,
                                            const float* __restrict__ be, float* __restrict__ y,
                                            float* __restrict__ slot) {
  const int row = blockIdx.x, t = threadIdx.x;
  const float4 v = ((const float4*)(x + (size_t)row * D_))[t];
  float s = v.x + v.y + v.z + v.w;
  float q = v.x * v.x + v.y * v.y + v.z * v.z + v.w * v.w;
  #pragma unroll
  for (int o = 32; o; o >>= 1) { s += __shfl_xor(s, o); q += __shfl_xor(q, o); }
  __shared__ float red[8];
  const int wid = t >> 6;
  if ((t & 63) == 0) { red[wid] = s; red[4 + wid] = q; }
  __syncthreads();
  s = red[0] + red[1] + red[2] + red[3];
  q = red[4] + red[5] + red[6] + red[7];
  const float mean = s * (1.f / D_);
  const float rstd = rsqrtf(q * (1.f / D_) - mean * mean + 1e-5f);
  const float4 gv = ((const float4*)g)[t];
  const float4 bv = ((const float4*)be)[t];
  float4 o;
  o.x = (v.x - mean) * rstd * gv.x + bv.x;
  o.y = (v.y - mean) * rstd * gv.y + bv.y;
  o.z = (v.z - mean) * rstd * gv.z + bv.z;
  o.w = (v.w - mean) * rstd * gv.w + bv.w;
  ((float4*)(y + (size_t)row * D_))[t] = o;
  float m = fmaxf(fmaxf(fabsf(o.x), fabsf(o.y)), fmaxf(fabsf(o.z), fabsf(o.w)));
  #pragma unroll
  for (int oo = 32; oo; oo >>= 1) m = fmaxf(m, __shfl_xor(m, oo));
  __syncthreads();                 // red reuse
  if ((t & 63) == 0) red[wid] = m;
  __syncthreads();
  if (t == 0) atomicMaxF(slot, fmaxf(fmaxf(red[0], red[1]), fmaxf(red[2], red[3])));
}

// ---------- GEMM: C[M,N] = A[M,K] @ B[N,K]^T (+bias, +mode epilogue) ----------
// tile (MT*32)x128, BK=32, 4 waves in 2x2, wave tile (MT*16)x64 = MTx4 frags.
// MT=4 -> 128x128 (big GEMMs); MT=2 -> 64x128 (N=1024 GEMMs: 512 blocks = 2/CU).
struct GemmArgs {
  const bf16* A;
  const bf16* B0; const bf16* B1; const bf16* B2;
  const float* bias0; const float* bias1; const float* bias2;
  void* out0; void* out1; void* out2;
  const float* res;   // MODE 1: residual (fp32, same layout as out)
  float* slot;        // MODE 2: absmax slot
  int K; int ldc;
};

// MODE 0: bf16 out (+bias), 3-way select by blockIdx.z (QKV fused);
//         z==2 (V) stores TRANSPOSED: [b][col][s] for attention's PV B-operand
// MODE 1: f32 out = acc + bias + res
// MODE 2: bf16 out = gelu(acc+bias), absmax -> slot
template <int MODE, int MT>
__global__ __launch_bounds__(256) void k_gemm(GemmArgs a) {
  constexpr int TM = MT * 32;
  __shared__ __align__(16) bf16 As[TM * 32];
  __shared__ __align__(16) bf16 Bs[128 * 32];
  const int t = threadIdx.x, wid = t >> 6, lane = t & 63;
  const int grp = lane >> 4, l15 = lane & 15;
  const int wm = wid >> 1, wn = wid & 1;
  const size_t m0 = (size_t)blockIdx.x * TM, n0 = (size_t)blockIdx.y * 128;
  const int K = a.K, ldc = a.ldc;

  const bf16* Bw; const float* bias; void* outv;
  if constexpr (MODE == 0) {
    const int z = blockIdx.z;
    Bw   = z == 0 ? a.B0 : (z == 1 ? a.B1 : a.B2);
    bias = z == 0 ? a.bias0 : (z == 1 ? a.bias1 : a.bias2);
    outv = z == 0 ? a.out0 : (z == 1 ? a.out1 : a.out2);
  } else {
    Bw = a.B0; bias = a.bias0; outv = a.out0;
  }

  const f32x4 zero = {0.f, 0.f, 0.f, 0.f};
  f32x4 acc[MT][4];
  #pragma unroll
  for (int m = 0; m < MT; m++)
    #pragma unroll
    for (int n = 0; n < 4; n++) acc[m][n] = zero;

  for (int kt = 0; kt < K; kt += 32) {
    // stage A tile (TM*64 B): MT/2 rounds of 1KB/wave; B tile (8KB): 2 rounds
    #pragma unroll
    for (int r = 0; r < MT / 2; r++) {
      const int ob  = (wid * (MT / 2) + r) * 1024 + lane * 16;
      const int row = ob >> 6;                            // 64B per row (32 bf16)
      const int col = (ob & 63) >> 1;
      gload16(a.A + (m0 + row) * (size_t)K + (kt + col),
              (char*)As + (size_t)(wid * (MT / 2) + r) * 1024);
    }
    #pragma unroll
    for (int r = 0; r < 2; r++) {
      const int ob  = (wid * 2 + r) * 1024 + lane * 16;
      const int row = ob >> 6;
      const int col = (ob & 63) >> 1;
      gload16(Bw + (n0 + row) * (size_t)K + (kt + col),
              (char*)Bs + (size_t)(wid * 2 + r) * 1024);
    }
    __syncthreads();   // drains vmcnt (global_load_lds) + lgkm
    bf16x8 af[MT], bfv[4];
    #pragma unroll
    for (int m = 0; m < MT; m++)
      af[m] = *(const bf16x8*)(As + (wm * (MT * 16) + m * 16 + l15) * 32 + grp * 8);
    #pragma unroll
    for (int n = 0; n < 4; n++)
      bfv[n] = *(const bf16x8*)(Bs + (wn * 64 + n * 16 + l15) * 32 + grp * 8);
    #pragma unroll
    for (int m = 0; m < MT; m++)
      #pragma unroll
      for (int n = 0; n < 4; n++)
        acc[m][n] = mfma16(af[m], bfv[n], acc[m][n]);
    __syncthreads();   // protect LDS before next stage
  }

  // epilogue: C/D frag layout: row=(lane>>4)*4+i, col=lane&15
  const size_t gr0 = m0 + wm * (MT * 16) + grp * 4;
  const size_t gc0 = n0 + wn * 64 + l15;

  if constexpr (MODE == 0) {
    if (blockIdx.z == 2) {
      // V^T store: out[b][gc][s] packed bf16x4 along s (i dimension)
      #pragma unroll
      for (int n = 0; n < 4; n++) {
        const size_t gc = gc0 + n * 16;
        const float bc = bias[gc];
        #pragma unroll
        for (int m = 0; m < MT; m++) {
          const size_t gr = gr0 + m * 16;              // tokens gr..gr+3, same batch
          const size_t bb = gr >> 11, s0 = gr & (S_ - 1);
          bf16x4 vv;
          #pragma unroll
          for (int i = 0; i < 4; i++) vv[i] = (bf16)(acc[m][n][i] + bc);
          *(bf16x4*)((bf16*)outv + bb * (size_t)D_ * S_ + gc * S_ + s0) = vv;
        }
      }
      return;
    }
  }

  float lmax = 0.f;
  #pragma unroll
  for (int n = 0; n < 4; n++) {
    const size_t gc = gc0 + n * 16;
    const float bc = bias[gc];
    #pragma unroll
    for (int m = 0; m < MT; m++) {
      const size_t gr = gr0 + m * 16;
      #pragma unroll
      for (int i = 0; i < 4; i++) {
        const float v = acc[m][n][i] + bc;
        const size_t idx = (gr + i) * (size_t)ldc + gc;
        if constexpr (MODE == 0) {
          ((bf16*)outv)[idx] = (bf16)v;
        } else if constexpr (MODE == 1) {
          ((float*)outv)[idx] = v + a.res[idx];
        } else {
          const float gl = 0.5f * v * (1.0f + erff(v * 0.7071067811865475f));
          ((bf16*)outv)[idx] = (bf16)gl;
          lmax = fmaxf(lmax, fabsf(gl));
        }
      }
    }
  }
  if constexpr (MODE == 2) {
    #pragma unroll
    for (int o = 32; o; o >>= 1) lmax = fmaxf(lmax, __shfl_xor(lmax, o));
    __shared__ float red[4];
    if (lane == 0) red[wid] = lmax;
    __syncthreads();
    if (t == 0) atomicMaxF(a.slot, fmaxf(fmaxf(red[0], red[1]), fmaxf(red[2], red[3])));
  }
}

// ---------- fused attention (flash-style), fp32 out + absmax ----------
// 4 waves x 32 q-rows = 128 q/block; KV tile = 64, K and V^T staged in LDS via
// global_load_lds (source-preswizzled T2), double-buffered, ONE barrier/tile.
// Mask loads are hoisted ABOVE the prefetch issue: vmcnt is in-order, so a wait
// for mask would otherwise drain the whole next-tile prefetch mid-tile.
__global__ __launch_bounds__(256) void k_attn(const bf16* __restrict__ qb, const bf16* __restrict__ kb,
                                              const bf16* __restrict__ vt, const float* __restrict__ mask,
                                              float* __restrict__ out, float* __restrict__ slot) {
  constexpr int PE = 72;                    // P row stride (64 + 8), 144B = 9*16B
  constexpr float SCL2 = 0.18033688f;       // 0.125 * log2(e)   (exp2 domain)
  constexpr float MSK2 = -14426.9504f;      // -10000 * log2(e)
  __shared__ __align__(16) bf16 Ks[2][64 * 64];   // [buf][key][d]  (chunk-swizzled)
  __shared__ __align__(16) bf16 Vs[2][64 * 64];   // [buf][d][key]  (chunk-swizzled)
  __shared__ __align__(16) bf16 Ps[4][32 * PE];   // per-wave P
  __shared__ float red[4];
  const int t = threadIdx.x, wid = t >> 6, lane = t & 63;
  const int grp = lane >> 4, l15 = lane & 15;
  const int b = blockIdx.y >> 4, h = blockIdx.y & 15;   // H = 16
  const size_t qkbase = ((size_t)b * S_) * D_ + (size_t)h * HD_;
  const size_t vtbase = (size_t)b * D_ * S_ + (size_t)h * HD_ * S_;
  const int q0 = blockIdx.x * 128 + wid * 32;
  bf16* __restrict__ myPs = Ps[wid];
  const int swzW = ((grp >> 1) & 1) << 4;   // P write: XOR col bit4 with row bit3
  const int swzR = ((l15 >> 3) & 1) << 4;   // P read:  row = l15

  bf16x8 qf[2][2];
  #pragma unroll
  for (int qi = 0; qi < 2; qi++)
    #pragma unroll
    for (int c = 0; c < 2; c++)
      qf[qi][c] = *(const bf16x8*)(qb + qkbase + (size_t)(q0 + qi * 16 + l15) * D_ +
                                   c * 32 + grp * 8);

  const f32x4 zero = {0.f, 0.f, 0.f, 0.f};
  f32x4 ao[2][4];
  float mi[2][4], li[2][4];
  #pragma unroll
  for (int qi = 0; qi < 2; qi++)
    #pragma unroll
    for (int i = 0; i < 4; i++) { ao[qi][i] = zero; mi[qi][i] = -INFINITY; li[qi][i] = 0.f; }

  // prologue: stage tile 0
  stage64(kb + qkbase, D_, Ks[0], t);
  stage64(vt + vtbase, S_, Vs[0], t);
  __syncthreads();
  int cur = 0;

  for (int kt0 = 0; kt0 < S_; kt0 += 64) {
    // mask loads FIRST (oldest in vmcnt order), then prefetch
    float mrow[4];
    #pragma unroll
    for (int nf = 0; nf < 4; nf++)
      mrow[nf] = mask[(size_t)b * S_ + kt0 + nf * 16 + l15];
    // prefetch next tile (overlaps full tile body, drained by tile-end barrier)
    if (kt0 + 64 < S_) {
      stage64(kb + qkbase + (size_t)(kt0 + 64) * D_, D_, Ks[cur ^ 1], t);
      stage64(vt + vtbase + (kt0 + 64), S_, Vs[cur ^ 1], t);
    }
    float madd[4];
    #pragma unroll
    for (int nf = 0; nf < 4; nf++) madd[nf] = (1.0f - mrow[nf]) * MSK2;

    // QK^T: 2 q-frags x 64 keys (K frag shared across q-frags)
    f32x4 accs[2][4];
    #pragma unroll
    for (int qi = 0; qi < 2; qi++)
      #pragma unroll
      for (int nf = 0; nf < 4; nf++) accs[qi][nf] = zero;
    #pragma unroll
    for (int nf = 0; nf < 4; nf++) {
      const int row = nf * 16 + l15;
      #pragma unroll
      for (int c = 0; c < 2; c++) {
        const int ch = (c * 4 + grp) ^ (l15 & 7);
        const bf16x8 kf = *(const bf16x8*)(&Ks[cur][row * 64 + ch * 8]);
        accs[0][nf] = mfma16(qf[0][c], kf, accs[0][nf]);
        accs[1][nf] = mfma16(qf[1][c], kf, accs[1][nf]);
      }
    }

    // online softmax (exp2 domain); li kept lane-partial (reduced in epilogue)
    float corr[2][4];
    #pragma unroll
    for (int qi = 0; qi < 2; qi++) {
      #pragma unroll
      for (int i = 0; i < 4; i++) {
        const float sc0 = accs[qi][0][i] * SCL2 + madd[0];
        const float sc1 = accs[qi][1][i] * SCL2 + madd[1];
        const float sc2 = accs[qi][2][i] * SCL2 + madd[2];
        const float sc3 = accs[qi][3][i] * SCL2 + madd[3];
        float mx = fmaxf(fmaxf(sc0, sc1), fmaxf(sc2, sc3));
        mx = rowmax16(mx);
        const float mnew = fmaxf(mi[qi][i], mx);
        const float co = exp2f(mi[qi][i] - mnew);
        corr[qi][i] = co;
        mi[qi][i] = mnew;
        const float p0 = exp2f(sc0 - mnew);
        const float p1 = exp2f(sc1 - mnew);
        const float p2 = exp2f(sc2 - mnew);
        const float p3 = exp2f(sc3 - mnew);
        li[qi][i] = li[qi][i] * co + ((p0 + p1) + (p2 + p3));
        const int rb = (qi * 16 + grp * 4 + i) * PE;
        myPs[rb + ((l15) ^ swzW)]      = (bf16)p0;
        myPs[rb + ((16 + l15) ^ swzW)] = (bf16)p1;
        myPs[rb + ((32 + l15) ^ swzW)] = (bf16)p2;
        myPs[rb + ((48 + l15) ^ swzW)] = (bf16)p3;
      }
    }
    #pragma unroll
    for (int qi = 0; qi < 2; qi++)
      #pragma unroll
      for (int nf = 0; nf < 4; nf++) {
        f32x4 aa = ao[qi][nf];
        aa[0] *= corr[qi][0]; aa[1] *= corr[qi][1];
        aa[2] *= corr[qi][2]; aa[3] *= corr[qi][3];
        ao[qi][nf] = aa;
      }

    // P @ V (V^T frag shared across q-frags)
    #pragma unroll
    for (int c = 0; c < 2; c++) {
      const int pc = (c * 32 + grp * 8) ^ swzR;
      const bf16x8 pa0 = *(const bf16x8*)(myPs + l15 * PE + pc);
      const bf16x8 pa1 = *(const bf16x8*)(myPs + (16 + l15) * PE + pc);
      #pragma unroll
      for (int nf = 0; nf < 4; nf++) {
        const int row = nf * 16 + l15;
        const int ch = (c * 4 + grp) ^ (l15 & 7);
        const bf16x8 bv = *(const bf16x8*)(&Vs[cur][row * 64 + ch * 8]);
        ao[0][nf] = mfma16(pa0, bv, ao[0][nf]);
        ao[1][nf] = mfma16(pa1, bv, ao[1][nf]);
      }
    }
    __syncthreads();   // next tile staged + LDS reuse safe
    cur ^= 1;
  }

  // epilogue: reduce li across the 16-lane group once, normalize, write, absmax
  float lmax = 0.f;
  #pragma unroll
  for (int qi = 0; qi < 2; qi++) {
    #pragma unroll
    for (int i = 0; i < 4; i++) {
      float l = li[qi][i];
      l += __shfl_xor(l, 1); l += __shfl_xor(l, 2);
      l += __shfl_xor(l, 4); l += __shfl_xor(l, 8);
      const float invl = 1.0f / l;
      #pragma unroll
      for (int nf = 0; nf < 4; nf++) {
        const float o = ao[qi][nf][i] * invl;
        out[qkbase + (size_t)(q0 + qi * 16 + grp * 4 + i) * D_ + nf * 16 + l15] = o;
        lmax = fmaxf(lmax, fabsf(o));
      }
    }
  }
  #pragma unroll
  for (int o = 32; o; o >>= 1) lmax = fmaxf(lmax, __shfl_xor(lmax, o));
  if (lane == 0) red[wid] = lmax;
  __syncthreads();
  if (t == 0) atomicMaxF(slot, fmaxf(fmaxf(red[0], red[1]), fmaxf(red[2], red[3])));
}

// ---------- launch ----------
extern "C" void kernel_launch(void* const* d_in, const int* in_sizes, int n_in,
                              void* d_out, int out_size, void* d_ws, size_t ws_size,
                              hipStream_t stream) {
  const float* hs   = (const float*)d_in[0];
  const float* mask = (const float*)d_in[1];
  const float* wq = (const float*)d_in[2];  const float* bq = (const float*)d_in[3];
  const float* wk = (const float*)d_in[4];  const float* bk = (const float*)d_in[5];
  const float* wv = (const float*)d_in[6];  const float* bv = (const float*)d_in[7];
  const float* wo = (const float*)d_in[8];  const float* bo = (const float*)d_in[9];
  const float* w1 = (const float*)d_in[10]; const float* b1 = (const float*)d_in[11];
  const float* w2 = (const float*)d_in[12]; const float* b2 = (const float*)d_in[13];
  const float* g1 = (const float*)d_in[14]; const float* be1 = (const float*)d_in[15];
  const float* g2 = (const float*)d_in[16]; const float* be2 = (const float*)d_in[17];
  const int* wbits = (const int*)d_in[18];
  const int* abits = (const int*)d_in[19];

  // workspace layout (bytes)
  char* ws = (char*)d_ws;
  size_t off = 0;
  float* scal = (float*)ws;                      off += 256;        // absmax slots
  float* fbuf = (float*)(ws + off);              off += (size_t)NT * D_ * 4;  // x1f/attnf/x2f
  bf16*  qx   = (bf16*)(ws + off);               off += (size_t)NT * D_ * 2;  // x1q/attnq/x2q
  bf16*  qb   = (bf16*)(ws + off);               off += (size_t)NT * D_ * 2;
  bf16*  kbuf = (bf16*)(ws + off);               off += (size_t)NT * D_ * 2;
  bf16*  vbuf = (bf16*)(ws + off);               off += (size_t)NT * D_ * 2;  // holds V^T
  float* h2   = (float*)(ws + off);              off += (size_t)NT * D_ * 4;  // attn residual out
  bf16*  h1   = (bf16*)(ws + off);               off += (size_t)NT * I_ * 2;  // gelu out (quant ip)
  bf16*  wqq  = (bf16*)(ws + off);               off += (size_t)D_ * D_ * 2;
  bf16*  wkq  = (bf16*)(ws + off);               off += (size_t)D_ * D_ * 2;
  bf16*  wvq  = (bf16*)(ws + off);               off += (size_t)D_ * D_ * 2;
  bf16*  woq  = (bf16*)(ws + off);               off += (size_t)D_ * D_ * 2;
  bf16*  w1q  = (bf16*)(ws + off);               off += (size_t)I_ * D_ * 2;
  bf16*  w2q  = (bf16*)(ws + off);               off += (size_t)D_ * I_ * 2;
  if (ws_size < off) return;  // insufficient workspace: fail cleanly

  // slots: 0 x1, 1 attn, 2 x2, 3 h1, 4..9 weights
  k_init<<<1, 64, 0, stream>>>(scal);

  const size_t nDD4 = (size_t)D_ * D_ / 4, nDI4 = (size_t)D_ * I_ / 4;
  WArgs wa;
  wa.w[0] = wq; wa.w[1] = wk; wa.w[2] = wv; wa.w[3] = wo; wa.w[4] = w1; wa.w[5] = w2;
  wa.q[0] = wqq; wa.q[1] = wkq; wa.q[2] = wvq; wa.q[3] = woq; wa.q[4] = w1q; wa.q[5] = w2q;
  wa.n4[0] = nDD4; wa.n4[1] = nDD4; wa.n4[2] = nDD4; wa.n4[3] = nDD4;
  wa.n4[4] = nDI4; wa.n4[5] = nDI4;
  k_absmax6<<<dim3(1024, 1, 6), 256, 0, stream>>>(wa, scal + 4);
  k_quant6<<<dim3(1024, 1, 6), 256, 0, stream>>>(wa, scal + 4, wbits);

  const size_t nND4 = (size_t)NT * D_ / 4;

  // LN1 -> fake-quant -> fused QKV GEMM (V written transposed)
  k_ln<<<NT, 256, 0, stream>>>(hs, g1, be1, fbuf, scal + 0);
  k_quant<<<2048, 256, 0, stream>>>(fbuf, qx, scal + 0, abits, nND4);
  {
    GemmArgs ga{};
    ga.A = qx; ga.B0 = wqq; ga.B1 = wkq; ga.B2 = wvq;
    ga.bias0 = bq; ga.bias1 = bk; ga.bias2 = bv;
    ga.out0 = qb; ga.out1 = kbuf; ga.out2 = vbuf;
    ga.K = D_; ga.ldc = D_;
    k_gemm<0, 4><<<dim3(NT / 128, D_ / 128, 3), 256, 0, stream>>>(ga);
  }

  // attention -> fake-quant -> out-proj (+residual)
  k_attn<<<dim3(S_ / 128, B_ * H_), 256, 0, stream>>>(qb, kbuf, vbuf, mask, fbuf, scal + 1);
  k_quant<<<2048, 256, 0, stream>>>(fbuf, qx, scal + 1, abits, nND4);
  {
    GemmArgs ga{};
    ga.A = qx; ga.B0 = woq; ga.bias0 = bo; ga.out0 = h2; ga.res = hs;
    ga.K = D_; ga.ldc = D_;
    k_gemm<1, 2><<<dim3(NT / 64, D_ / 128), 256, 0, stream>>>(ga);
  }

  // LN2 -> fake-quant -> MLP1 (gelu + absmax) -> fake-quant -> MLP2 (+residual)
  k_ln<<<NT, 256, 0, stream>>>(h2, g2, be2, fbuf, scal + 2);
  k_quant<<<2048, 256, 0, stream>>>(fbuf, qx, scal + 2, abits, nND4);
  {
    GemmArgs ga{};
    ga.A = qx; ga.B0 = w1q; ga.bias0 = b1; ga.out0 = h1; ga.slot = scal + 3;
    ga.K = D_; ga.ldc = I_;
    k_gemm<2, 4><<<dim3(NT / 128, I_ / 128), 256, 0, stream>>>(ga);
  }
  k_quant_ip<<<(NT * (size_t)I_ / 8 + 255) / 256, 256, 0, stream>>>(h1, scal + 3, abits,
                                                                    (size_t)NT * I_ / 8);
  {
    GemmArgs ga{};
    ga.A = h1; ga.B0 = w2q; ga.bias0 = b2; ga.out0 = d_out; ga.res = h2;
    ga.K = I_; ga.ldc = D_;
    k_gemm<1, 2><<<dim3(NT / 64, D_ / 128), 256, 0, stream>>>(ga);
  }
}

// Round 5
// 535.619 us; speedup vs baseline: 1.4825x; 1.0472x over previous
//
#include <hip/hip_runtime.h>
#include <hip/hip_bf16.h>
#include <math.h>

typedef __bf16 bf16;
typedef __bf16 bf16x8 __attribute__((ext_vector_type(8)));
typedef __bf16 bf16x4 __attribute__((ext_vector_type(4)));
typedef float  f32x4  __attribute__((ext_vector_type(4)));
typedef float  f32x16 __attribute__((ext_vector_type(16)));
typedef unsigned int u32x4 __attribute__((ext_vector_type(4)));

static constexpr int B_  = 2;
static constexpr int S_  = 2048;
static constexpr int D_  = 1024;
static constexpr int H_  = 16;
static constexpr int HD_ = 64;
static constexpr int I_  = 4096;
static constexpr int NT  = B_ * S_;       // 4096 tokens

// ---------- helpers ----------
__device__ __forceinline__ void atomicMaxF(float* p, float v) {
  // v >= 0 always (absmax), so uint bit-order == float order
  atomicMax((unsigned int*)p, __float_as_uint(v));
}

__device__ __forceinline__ f32x4 mfma16(bf16x8 a, bf16x8 b, f32x4 c) {
  return __builtin_amdgcn_mfma_f32_16x16x32_bf16(a, b, c, 0, 0, 0);
}

__device__ __forceinline__ f32x16 mfma32(bf16x8 a, bf16x8 b, f32x16 c) {
  return __builtin_amdgcn_mfma_f32_32x32x16_bf16(a, b, c, 0, 0, 0);
}

__device__ __forceinline__ void gload16(const void* g, void* lds) {
  // async global->LDS, 16B/lane; LDS dest = wave-uniform base + lane*16
  __builtin_amdgcn_global_load_lds(
      (const __attribute__((address_space(1))) void*)g,
      (__attribute__((address_space(3))) void*)lds, 16, 0, 0);
}

__device__ __forceinline__ float quant1(float x, float scale, float qmax) {
  // matches jnp: round(clip(x/scale,-qmax,qmax))*scale, RNE rounding
  return rintf(fminf(fmaxf(x / scale, -qmax), qmax)) * scale;
}

// stage a 64x64 bf16 tile into LDS with a 128-thread block; XOR swizzle
// (chunk ^= row&7) applied on the GLOBAL source, LDS dest stays linear.
__device__ __forceinline__ void stage64b(const bf16* __restrict__ g, int rs, bf16* lds, int t) {
  #pragma unroll
  for (int r = 0; r < 4; r++) {
    const int cl  = r * 128 + t;           // 16B-chunk id in tile (512 total)
    const int row = cl >> 3;               // 8 chunks per 128B row
    const int scr = (cl & 7) ^ (row & 7);  // pre-swizzled source chunk
    gload16(g + (size_t)row * rs + scr * 8,
            (char*)lds + (size_t)(r * 128 + (t & 64)) * 16);
  }
}

// ---------- madd precompute + scalar-slot init ----------
__global__ __launch_bounds__(256) void k_prep(const float* __restrict__ mask,
                                              float* __restrict__ madd, float* __restrict__ scal) {
  constexpr float MSK2 = -14426.950408889634f;   // -10000 * log2(e)
  const int i = blockIdx.x * 256 + threadIdx.x;
  if (blockIdx.x == 0 && threadIdx.x < 32) scal[threadIdx.x] = 0.f;
  if (i < B_ * S_) madd[i] = (1.0f - mask[i]) * MSK2;
}

// ---------- fused per-tensor absmax + quant for the 6 weights ----------
struct WArgs {
  const float* w[6];
  bf16* q[6];
  size_t n4[6];
};

__global__ __launch_bounds__(256) void k_absmax6(WArgs a, float* __restrict__ slots) {
  const int z = blockIdx.z;
  const float* __restrict__ x = a.w[z];
  const size_t n4 = a.n4[z];
  size_t i = (size_t)blockIdx.x * 256 + threadIdx.x;
  const size_t stride = (size_t)gridDim.x * 256;
  float m = 0.f;
  for (; i < n4; i += stride) {
    float4 v = ((const float4*)x)[i];
    m = fmaxf(m, fmaxf(fmaxf(fabsf(v.x), fabsf(v.y)), fmaxf(fabsf(v.z), fabsf(v.w))));
  }
  #pragma unroll
  for (int o = 32; o; o >>= 1) m = fmaxf(m, __shfl_xor(m, o));
  __shared__ float red[4];
  if ((threadIdx.x & 63) == 0) red[threadIdx.x >> 6] = m;
  __syncthreads();
  if (threadIdx.x == 0)
    atomicMaxF(slots + z, fmaxf(fmaxf(red[0], red[1]), fmaxf(red[2], red[3])));
}

__global__ __launch_bounds__(256) void k_quant6(WArgs a, const float* __restrict__ slots,
                                                const int* __restrict__ bits) {
  const int z = blockIdx.z;
  const float* __restrict__ x = a.w[z];
  bf16* __restrict__ y = a.q[z];
  const size_t n4 = a.n4[z];
  const float qmax  = (float)((1 << (*bits - 1)) - 1);
  const float scale = fmaxf(slots[z], 1e-8f) / qmax;
  size_t i = (size_t)blockIdx.x * 256 + threadIdx.x;
  const size_t stride = (size_t)gridDim.x * 256;
  for (; i < n4; i += stride) {
    float4 v = ((const float4*)x)[i];
    bf16x4 o;
    o[0] = (bf16)quant1(v.x, scale, qmax);
    o[1] = (bf16)quant1(v.y, scale, qmax);
    o[2] = (bf16)quant1(v.z, scale, qmax);
    o[3] = (bf16)quant1(v.w, scale, qmax);
    ((bf16x4*)y)[i] = o;
  }
}

// ---------- fake-quant fp32 -> bf16 (activations) ----------
__global__ __launch_bounds__(256) void k_quant(const float* __restrict__ x, bf16* __restrict__ y,
                                               const float* __restrict__ slot,
                                               const int* __restrict__ bits, size_t n4) {
  const float qmax  = (float)((1 << (*bits - 1)) - 1);
  const float scale = fmaxf(*slot, 1e-8f) / qmax;
  size_t i = (size_t)blockIdx.x * 256 + threadIdx.x;
  const size_t stride = (size_t)gridDim.x * 256;
  for (; i < n4; i += stride) {
    float4 v = ((const float4*)x)[i];
    bf16x4 o;
    o[0] = (bf16)quant1(v.x, scale, qmax);
    o[1] = (bf16)quant1(v.y, scale, qmax);
    o[2] = (bf16)quant1(v.z, scale, qmax);
    o[3] = (bf16)quant1(v.w, scale, qmax);
    ((bf16x4*)y)[i] = o;
  }
}

// ---------- fake-quant bf16 in-place (GELU output) ----------
__global__ __launch_bounds__(256) void k_quant_ip(bf16* __restrict__ x,
                                                  const float* __restrict__ slot,
                                                  const int* __restrict__ bits, size_t n8) {
  const float qmax  = (float)((1 << (*bits - 1)) - 1);
  const float scale = fmaxf(*slot, 1e-8f) / qmax;
  size_t i = (size_t)blockIdx.x * 256 + threadIdx.x;
  if (i >= n8) return;
  bf16x8 v = ((const bf16x8*)x)[i];
  #pragma unroll
  for (int j = 0; j < 8; j++) v[j] = (bf16)quant1((float)v[j], scale, qmax);
  ((bf16x8*)x)[i] = v;
}

// ---------- LayerNorm (fp32 out, + absmax) : one block per row ----------
__global__ __launch_bounds__(256) void k_ln(const float* __restrict__ x, const float* __restrict__ g,
                                            const float* __restrict__ be, float* __restrict__ y,
                                            float* __restrict__ slot) {
  const int row = blockIdx.x, t = threadIdx.x;
  const float4 v = ((const float4*)(x + (size_t)row * D_))[t];
  float s = v.x + v.y + v.z + v.w;
  float q = v.x * v.x + v.y * v.y + v.z * v.z + v.w * v.w;
  #pragma unroll
  for (int o = 32; o; o >>= 1) { s += __shfl_xor(s, o); q += __shfl_xor(q, o); }
  __shared__ float red[8];
  const int wid = t >> 6;
  if ((t & 63) == 0) { red[wid] = s; red[4 + wid] = q; }
  __syncthreads();
  s = red[0] + red[1] + red[2] + red[3];
  q = red[4] + red[5] + red[6] + red[7];
  const float mean = s * (1.f / D_);
  const float rstd = rsqrtf(q * (1.f / D_) - mean * mean + 1e-5f);
  const float4 gv = ((const float4*)g)[t];
  const float4 bv = ((const float4*)be)[t];
  float4 o;
  o.x = (v.x - mean) * rstd * gv.x + bv.x;
  o.y = (v.y - mean) * rstd * gv.y + bv.y;
  o.z = (v.z - mean) * rstd * gv.z + bv.z;
  o.w = (v.w - mean) * rstd * gv.w + bv.w;
  ((float4*)(y + (size_t)row * D_))[t] = o;
  float m = fmaxf(fmaxf(fabsf(o.x), fabsf(o.y)), fmaxf(fabsf(o.z), fabsf(o.w)));
  #pragma unroll
  for (int oo = 32; oo; oo >>= 1) m = fmaxf(m, __shfl_xor(m, oo));
  __syncthreads();                 // red reuse
  if ((t & 63) == 0) red[wid] = m;
  __syncthreads();
  if (t == 0) atomicMaxF(slot, fmaxf(fmaxf(red[0], red[1]), fmaxf(red[2], red[3])));
}

// ---------- GEMM: C[M,N] = A[M,K] @ B[N,K]^T (+bias, +mode epilogue) ----------
// tile (MT*32)x128, BK=32, 4 waves in 2x2, wave tile (MT*16)x64 = MTx4 frags.
// MT=4 -> 128x128 (big GEMMs); MT=2 -> 64x128 (N=1024 GEMMs: 512 blocks = 2/CU).
struct GemmArgs {
  const bf16* A;
  const bf16* B0; const bf16* B1; const bf16* B2;
  const float* bias0; const float* bias1; const float* bias2;
  void* out0; void* out1; void* out2;
  const float* res;   // MODE 1: residual (fp32, same layout as out)
  float* slot;        // MODE 2: absmax slot
  int K; int ldc;
};

// MODE 0: bf16 out (+bias), 3-way select by blockIdx.z (QKV fused);
//         z==2 (V) stores TRANSPOSED: [b][col][s] for attention's PV B-operand
// MODE 1: f32 out = acc + bias + res
// MODE 2: bf16 out = gelu(acc+bias), absmax -> slot
template <int MODE, int MT>
__global__ __launch_bounds__(256) void k_gemm(GemmArgs a) {
  constexpr int TM = MT * 32;
  __shared__ __align__(16) bf16 As[TM * 32];
  __shared__ __align__(16) bf16 Bs[128 * 32];
  const int t = threadIdx.x, wid = t >> 6, lane = t & 63;
  const int grp = lane >> 4, l15 = lane & 15;
  const int wm = wid >> 1, wn = wid & 1;
  const size_t m0 = (size_t)blockIdx.x * TM, n0 = (size_t)blockIdx.y * 128;
  const int K = a.K, ldc = a.ldc;

  const bf16* Bw; const float* bias; void* outv;
  if constexpr (MODE == 0) {
    const int z = blockIdx.z;
    Bw   = z == 0 ? a.B0 : (z == 1 ? a.B1 : a.B2);
    bias = z == 0 ? a.bias0 : (z == 1 ? a.bias1 : a.bias2);
    outv = z == 0 ? a.out0 : (z == 1 ? a.out1 : a.out2);
  } else {
    Bw = a.B0; bias = a.bias0; outv = a.out0;
  }

  const f32x4 zero = {0.f, 0.f, 0.f, 0.f};
  f32x4 acc[MT][4];
  #pragma unroll
  for (int m = 0; m < MT; m++)
    #pragma unroll
    for (int n = 0; n < 4; n++) acc[m][n] = zero;

  for (int kt = 0; kt < K; kt += 32) {
    // stage A tile (TM*64 B): MT/2 rounds of 1KB/wave; B tile (8KB): 2 rounds
    #pragma unroll
    for (int r = 0; r < MT / 2; r++) {
      const int ob  = (wid * (MT / 2) + r) * 1024 + lane * 16;
      const int row = ob >> 6;                            // 64B per row (32 bf16)
      const int col = (ob & 63) >> 1;
      gload16(a.A + (m0 + row) * (size_t)K + (kt + col),
              (char*)As + (size_t)(wid * (MT / 2) + r) * 1024);
    }
    #pragma unroll
    for (int r = 0; r < 2; r++) {
      const int ob  = (wid * 2 + r) * 1024 + lane * 16;
      const int row = ob >> 6;
      const int col = (ob & 63) >> 1;
      gload16(Bw + (n0 + row) * (size_t)K + (kt + col),
              (char*)Bs + (size_t)(wid * 2 + r) * 1024);
    }
    __syncthreads();   // drains vmcnt (global_load_lds) + lgkm
    bf16x8 af[MT], bfv[4];
    #pragma unroll
    for (int m = 0; m < MT; m++)
      af[m] = *(const bf16x8*)(As + (wm * (MT * 16) + m * 16 + l15) * 32 + grp * 8);
    #pragma unroll
    for (int n = 0; n < 4; n++)
      bfv[n] = *(const bf16x8*)(Bs + (wn * 64 + n * 16 + l15) * 32 + grp * 8);
    #pragma unroll
    for (int m = 0; m < MT; m++)
      #pragma unroll
      for (int n = 0; n < 4; n++)
        acc[m][n] = mfma16(af[m], bfv[n], acc[m][n]);
    __syncthreads();   // protect LDS before next stage
  }

  // epilogue: C/D frag layout: row=(lane>>4)*4+i, col=lane&15
  const size_t gr0 = m0 + wm * (MT * 16) + grp * 4;
  const size_t gc0 = n0 + wn * 64 + l15;

  if constexpr (MODE == 0) {
    if (blockIdx.z == 2) {
      // V^T store: out[b][gc][s] packed bf16x4 along s (i dimension)
      #pragma unroll
      for (int n = 0; n < 4; n++) {
        const size_t gc = gc0 + n * 16;
        const float bc = bias[gc];
        #pragma unroll
        for (int m = 0; m < MT; m++) {
          const size_t gr = gr0 + m * 16;              // tokens gr..gr+3, same batch
          const size_t bb = gr >> 11, s0 = gr & (S_ - 1);
          bf16x4 vv;
          #pragma unroll
          for (int i = 0; i < 4; i++) vv[i] = (bf16)(acc[m][n][i] + bc);
          *(bf16x4*)((bf16*)outv + bb * (size_t)D_ * S_ + gc * S_ + s0) = vv;
        }
      }
      return;
    }
  }

  float lmax = 0.f;
  #pragma unroll
  for (int n = 0; n < 4; n++) {
    const size_t gc = gc0 + n * 16;
    const float bc = bias[gc];
    #pragma unroll
    for (int m = 0; m < MT; m++) {
      const size_t gr = gr0 + m * 16;
      #pragma unroll
      for (int i = 0; i < 4; i++) {
        const float v = acc[m][n][i] + bc;
        const size_t idx = (gr + i) * (size_t)ldc + gc;
        if constexpr (MODE == 0) {
          ((bf16*)outv)[idx] = (bf16)v;
        } else if constexpr (MODE == 1) {
          ((float*)outv)[idx] = v + a.res[idx];
        } else {
          const float gl = 0.5f * v * (1.0f + erff(v * 0.7071067811865475f));
          ((bf16*)outv)[idx] = (bf16)gl;
          lmax = fmaxf(lmax, fabsf(gl));
        }
      }
    }
  }
  if constexpr (MODE == 2) {
    #pragma unroll
    for (int o = 32; o; o >>= 1) lmax = fmaxf(lmax, __shfl_xor(lmax, o));
    __shared__ float red[4];
    if (lane == 0) red[wid] = lmax;
    __syncthreads();
    if (t == 0) atomicMaxF(a.slot, fmaxf(fmaxf(red[0], red[1]), fmaxf(red[2], red[3])));
  }
}

// ---------- fused attention (flash, swapped-operand 32x32 MFMA) ----------
// 2 waves x 32 q-rows = 64 q/block; KV tile 64 double-buffered in LDS.
// Swapped QK^T (mfma(K,Q)) puts each q-row's scores lane-local: softmax is
// in-register (one xor-32 exchange per tile). P repacked straight into the
// PV B-operand via v_cvt_pk_bf16_f32 + v_permlane32_swap (T12) — no P LDS.
// PV is swapped too (mfma(V^T,P)) so O/mi/li stay per-lane. Defer-max (T13).
__global__ __launch_bounds__(128) void k_attn(const bf16* __restrict__ qb, const bf16* __restrict__ kb,
                                              const bf16* __restrict__ vt, const float* __restrict__ madd,
                                              float* __restrict__ out, float* __restrict__ slot) {
  constexpr float SCL2 = 0.18033688011112042f;   // 0.125 * log2(e)  (exp2 domain)
  constexpr float THR  = 8.0f;                   // defer-max threshold (log2 units)
  __shared__ __align__(16) bf16 Ks[2][64 * 64];  // [buf][key][d]  (chunk-swizzled)
  __shared__ __align__(16) bf16 Vs[2][64 * 64];  // [buf][d][key]  (chunk-swizzled)
  __shared__ float red[2];
  const int t = threadIdx.x, wid = t >> 6, lane = t & 63;
  const int l31 = lane & 31, hi = lane >> 5;
  const int b = blockIdx.y >> 4, h = blockIdx.y & 15;   // H = 16
  const size_t qkbase = ((size_t)b * S_) * D_ + (size_t)h * HD_;
  const size_t vtbase = (size_t)b * D_ * S_ + (size_t)h * HD_ * S_;
  const int q = blockIdx.x * 64 + wid * 32 + l31;       // this lane's q-row

  // Q fragments: B-operand of mfma(K,Q): col=q (lane-local), k = j*16 + hi*8 + e
  bf16x8 qf[4];
  #pragma unroll
  for (int j = 0; j < 4; j++)
    qf[j] = *(const bf16x8*)(qb + qkbase + (size_t)q * D_ + j * 16 + hi * 8);

  f32x16 ao0, ao1;
  #pragma unroll
  for (int r = 0; r < 16; r++) { ao0[r] = 0.f; ao1[r] = 0.f; }
  float mi = -INFINITY, li = 0.f;

  // prologue: stage tile 0
  stage64b(kb + qkbase, D_, Ks[0], t);
  stage64b(vt + vtbase, S_, Vs[0], t);
  __syncthreads();
  int cur = 0;

  const float* mp = madd + (size_t)b * S_ + hi * 4;

  for (int kt0 = 0; kt0 < S_; kt0 += 64) {
    // madd loads FIRST (vmcnt-oldest), fence, then prefetch: the mid-tile wait
    // for madd is then vmcnt(8) and never drains the prefetch.
    f32x4 mv[2][4];
    #pragma unroll
    for (int kb2 = 0; kb2 < 2; kb2++)
      #pragma unroll
      for (int g = 0; g < 4; g++)
        mv[kb2][g] = *(const f32x4*)(mp + kt0 + kb2 * 32 + g * 8);
    __builtin_amdgcn_sched_barrier(0);
    if (kt0 + 64 < S_) {
      stage64b(kb + qkbase + (size_t)(kt0 + 64) * D_, D_, Ks[cur ^ 1], t);
      stage64b(vt + vtbase + (kt0 + 64), S_, Vs[cur ^ 1], t);
    }

    // QK^T swapped: D[row=key][col=q].  s0 = keys 0..31, s1 = keys 32..63
    f32x16 s0, s1;
    #pragma unroll
    for (int r = 0; r < 16; r++) { s0[r] = 0.f; s1[r] = 0.f; }
    #pragma unroll
    for (int j = 0; j < 4; j++) {
      const int ch = (j * 2 + hi);
      const bf16x8 kf0 = *(const bf16x8*)(&Ks[cur][l31 * 64 + (ch ^ (l31 & 7)) * 8]);
      const bf16x8 kf1 = *(const bf16x8*)(&Ks[cur][(32 + l31) * 64 + (ch ^ (l31 & 7)) * 8]);
      s0 = mfma32(kf0, qf[j], s0);
      s1 = mfma32(kf1, qf[j], s1);
    }

    // scores (exp2 domain) + mask; key(r) = (r&3) + 8*(r>>2) + 4*hi (+32 for s1)
    float pv_[32];
    #pragma unroll
    for (int r = 0; r < 16; r++) pv_[r]      = s0[r] * SCL2 + mv[0][r >> 2][r & 3];
    #pragma unroll
    for (int r = 0; r < 16; r++) pv_[16 + r] = s1[r] * SCL2 + mv[1][r >> 2][r & 3];

    // in-register row max + one cross-pair exchange
    float mx = pv_[0];
    #pragma unroll
    for (int r = 1; r < 32; r++) mx = fmaxf(mx, pv_[r]);
    mx = fmaxf(mx, __shfl_xor(mx, 32));

    if (!__all(mx - mi <= THR)) {        // defer-max: rescale only when needed
      const float mnew = fmaxf(mi, mx);
      const float co = exp2f(mi - mnew);
      li *= co;
      #pragma unroll
      for (int r = 0; r < 16; r++) { ao0[r] *= co; ao1[r] *= co; }
      mi = mnew;
    }

    float ls = 0.f;
    #pragma unroll
    for (int r = 0; r < 32; r++) { pv_[r] = exp2f(pv_[r] - mi); ls += pv_[r]; }
    li += ls;

    // pack P -> PV B-operand frags: cvt_pk pairs, then permlane32 swaps
    unsigned pk[16];
    #pragma unroll
    for (int tt = 0; tt < 8; tt++) {
      asm("v_cvt_pk_bf16_f32 %0, %1, %2" : "=v"(pk[tt])     : "v"(pv_[2 * tt]),      "v"(pv_[2 * tt + 1]));
      asm("v_cvt_pk_bf16_f32 %0, %1, %2" : "=v"(pk[8 + tt]) : "v"(pv_[16 + 2 * tt]), "v"(pv_[16 + 2 * tt + 1]));
    }
    #pragma unroll
    for (int g = 0; g < 4; g++) {
      asm volatile("v_permlane32_swap_b32 %0, %1" : "+v"(pk[4 * g]),     "+v"(pk[4 * g + 2]));
      asm volatile("v_permlane32_swap_b32 %0, %1" : "+v"(pk[4 * g + 1]), "+v"(pk[4 * g + 3]));
    }

    // PV swapped: D[row=d][col=q];  frag j covers keys j*16 .. j*16+15
    #pragma unroll
    for (int j = 0; j < 4; j++) {
      const u32x4 w = {pk[4 * j], pk[4 * j + 1], pk[4 * j + 2], pk[4 * j + 3]};
      const bf16x8 pf = __builtin_bit_cast(bf16x8, w);
      const int ch = (j * 2 + hi);
      const bf16x8 vf0 = *(const bf16x8*)(&Vs[cur][l31 * 64 + (ch ^ (l31 & 7)) * 8]);
      const bf16x8 vf1 = *(const bf16x8*)(&Vs[cur][(32 + l31) * 64 + (ch ^ (l31 & 7)) * 8]);
      ao0 = mfma32(vf0, pf, ao0);
      ao1 = mfma32(vf1, pf, ao1);
    }
    __syncthreads();   // prefetch landed + all waves done reading cur
    cur ^= 1;
  }

  // epilogue: join the hi-pair's li, normalize, write fp32, absmax
  li += __shfl_xor(li, 32);
  const float invl = 1.0f / li;
  float lmax = 0.f;
  float* orow = out + qkbase + (size_t)q * D_;
  #pragma unroll
  for (int db2 = 0; db2 < 2; db2++) {
    #pragma unroll
    for (int rg = 0; rg < 4; rg++) {
      float4 o;
      o.x = (db2 ? ao1[rg * 4 + 0] : ao0[rg * 4 + 0]) * invl;
      o.y = (db2 ? ao1[rg * 4 + 1] : ao0[rg * 4 + 1]) * invl;
      o.z = (db2 ? ao1[rg * 4 + 2] : ao0[rg * 4 + 2]) * invl;
      o.w = (db2 ? ao1[rg * 4 + 3] : ao0[rg * 4 + 3]) * invl;
      *(float4*)(orow + db2 * 32 + rg * 8 + hi * 4) = o;
      lmax = fmaxf(lmax, fmaxf(fmaxf(fabsf(o.x), fabsf(o.y)), fmaxf(fabsf(o.z), fabsf(o.w))));
    }
  }
  #pragma unroll
  for (int o = 32; o; o >>= 1) lmax = fmaxf(lmax, __shfl_xor(lmax, o));
  if (lane == 0) red[wid] = lmax;
  __syncthreads();
  if (t == 0) atomicMaxF(slot, fmaxf(red[0], red[1]));
}

// ---------- launch ----------
extern "C" void kernel_launch(void* const* d_in, const int* in_sizes, int n_in,
                              void* d_out, int out_size, void* d_ws, size_t ws_size,
                              hipStream_t stream) {
  const float* hs   = (const float*)d_in[0];
  const float* mask = (const float*)d_in[1];
  const float* wq = (const float*)d_in[2];  const float* bq = (const float*)d_in[3];
  const float* wk = (const float*)d_in[4];  const float* bk = (const float*)d_in[5];
  const float* wv = (const float*)d_in[6];  const float* bv = (const float*)d_in[7];
  const float* wo = (const float*)d_in[8];  const float* bo = (const float*)d_in[9];
  const float* w1 = (const float*)d_in[10]; const float* b1 = (const float*)d_in[11];
  const float* w2 = (const float*)d_in[12]; const float* b2 = (const float*)d_in[13];
  const float* g1 = (const float*)d_in[14]; const float* be1 = (const float*)d_in[15];
  const float* g2 = (const float*)d_in[16]; const float* be2 = (const float*)d_in[17];
  const int* wbits = (const int*)d_in[18];
  const int* abits = (const int*)d_in[19];

  // workspace layout (bytes)
  char* ws = (char*)d_ws;
  size_t off = 0;
  float* scal = (float*)ws;                      off += 256;        // absmax slots
  float* maddg= (float*)(ws + off);              off += (size_t)NT * 4;       // (1-mask)*MSK2
  float* fbuf = (float*)(ws + off);              off += (size_t)NT * D_ * 4;  // x1f/attnf/x2f
  bf16*  qx   = (bf16*)(ws + off);               off += (size_t)NT * D_ * 2;  // x1q/attnq/x2q
  bf16*  qb   = (bf16*)(ws + off);               off += (size_t)NT * D_ * 2;
  bf16*  kbuf = (bf16*)(ws + off);               off += (size_t)NT * D_ * 2;
  bf16*  vbuf = (bf16*)(ws + off);               off += (size_t)NT * D_ * 2;  // holds V^T
  float* h2   = (float*)(ws + off);              off += (size_t)NT * D_ * 4;  // attn residual out
  bf16*  h1   = (bf16*)(ws + off);               off += (size_t)NT * I_ * 2;  // gelu out (quant ip)
  bf16*  wqq  = (bf16*)(ws + off);               off += (size_t)D_ * D_ * 2;
  bf16*  wkq  = (bf16*)(ws + off);               off += (size_t)D_ * D_ * 2;
  bf16*  wvq  = (bf16*)(ws + off);               off += (size_t)D_ * D_ * 2;
  bf16*  woq  = (bf16*)(ws + off);               off += (size_t)D_ * D_ * 2;
  bf16*  w1q  = (bf16*)(ws + off);               off += (size_t)I_ * D_ * 2;
  bf16*  w2q  = (bf16*)(ws + off);               off += (size_t)D_ * I_ * 2;
  if (ws_size < off) return;  // insufficient workspace: fail cleanly

  // slots: 0 x1, 1 attn, 2 x2, 3 h1, 4..9 weights
  k_prep<<<NT / 256, 256, 0, stream>>>(mask, maddg, scal);

  const size_t nDD4 = (size_t)D_ * D_ / 4, nDI4 = (size_t)D_ * I_ / 4;
  WArgs wa;
  wa.w[0] = wq; wa.w[1] = wk; wa.w[2] = wv; wa.w[3] = wo; wa.w[4] = w1; wa.w[5] = w2;
  wa.q[0] = wqq; wa.q[1] = wkq; wa.q[2] = wvq; wa.q[3] = woq; wa.q[4] = w1q; wa.q[5] = w2q;
  wa.n4[0] = nDD4; wa.n4[1] = nDD4; wa.n4[2] = nDD4; wa.n4[3] = nDD4;
  wa.n4[4] = nDI4; wa.n4[5] = nDI4;
  k_absmax6<<<dim3(1024, 1, 6), 256, 0, stream>>>(wa, scal + 4);
  k_quant6<<<dim3(1024, 1, 6), 256, 0, stream>>>(wa, scal + 4, wbits);

  const size_t nND4 = (size_t)NT * D_ / 4;

  // LN1 -> fake-quant -> fused QKV GEMM (V written transposed)
  k_ln<<<NT, 256, 0, stream>>>(hs, g1, be1, fbuf, scal + 0);
  k_quant<<<2048, 256, 0, stream>>>(fbuf, qx, scal + 0, abits, nND4);
  {
    GemmArgs ga{};
    ga.A = qx; ga.B0 = wqq; ga.B1 = wkq; ga.B2 = wvq;
    ga.bias0 = bq; ga.bias1 = bk; ga.bias2 = bv;
    ga.out0 = qb; ga.out1 = kbuf; ga.out2 = vbuf;
    ga.K = D_; ga.ldc = D_;
    k_gemm<0, 4><<<dim3(NT / 128, D_ / 128, 3), 256, 0, stream>>>(ga);
  }

  // attention -> fake-quant -> out-proj (+residual)
  k_attn<<<dim3(S_ / 64, B_ * H_), 128, 0, stream>>>(qb, kbuf, vbuf, maddg, fbuf, scal + 1);
  k_quant<<<2048, 256, 0, stream>>>(fbuf, qx, scal + 1, abits, nND4);
  {
    GemmArgs ga{};
    ga.A = qx; ga.B0 = woq; ga.bias0 = bo; ga.out0 = h2; ga.res = hs;
    ga.K = D_; ga.ldc = D_;
    k_gemm<1, 2><<<dim3(NT / 64, D_ / 128), 256, 0, stream>>>(ga);
  }

  // LN2 -> fake-quant -> MLP1 (gelu + absmax) -> fake-quant -> MLP2 (+residual)
  k_ln<<<NT, 256, 0, stream>>>(h2, g2, be2, fbuf, scal + 2);
  k_quant<<<2048, 256, 0, stream>>>(fbuf, qx, scal + 2, abits, nND4);
  {
    GemmArgs ga{};
    ga.A = qx; ga.B0 = w1q; ga.bias0 = b1; ga.out0 = h1; ga.slot = scal + 3;
    ga.K = D_; ga.ldc = I_;
    k_gemm<2, 4><<<dim3(NT / 128, I_ / 128), 256, 0, stream>>>(ga);
  }
  k_quant_ip<<<(NT * (size_t)I_ / 8 + 255) / 256, 256, 0, stream>>>(h1, scal + 3, abits,
                                                                    (size_t)NT * I_ / 8);
  {
    GemmArgs ga{};
    ga.A = h1; ga.B0 = w2q; ga.bias0 = b2; ga.out0 = d_out; ga.res = h2;
    ga.K = I_; ga.ldc = D_;
    k_gemm<1, 2><<<dim3(NT / 64, D_ / 128), 256, 0, stream>>>(ga);
  }
}

// Round 6
// 495.099 us; speedup vs baseline: 1.6038x; 1.0818x over previous
//
#include <hip/hip_runtime.h>
#include <hip/hip_bf16.h>
#include <math.h>

typedef __bf16 bf16;
typedef __bf16 bf16x8 __attribute__((ext_vector_type(8)));
typedef __bf16 bf16x4 __attribute__((ext_vector_type(4)));
typedef float  f32x4  __attribute__((ext_vector_type(4)));
typedef float  f32x16 __attribute__((ext_vector_type(16)));
typedef unsigned int u32x4 __attribute__((ext_vector_type(4)));

static constexpr int B_  = 2;
static constexpr int S_  = 2048;
static constexpr int D_  = 1024;
static constexpr int H_  = 16;
static constexpr int HD_ = 64;
static constexpr int I_  = 4096;
static constexpr int NT  = B_ * S_;       // 4096 tokens

// ---------- helpers ----------
__device__ __forceinline__ void atomicMaxF(float* p, float v) {
  atomicMax((unsigned int*)p, __float_as_uint(v));   // v >= 0 always
}

__device__ __forceinline__ f32x4 mfma16(bf16x8 a, bf16x8 b, f32x4 c) {
  return __builtin_amdgcn_mfma_f32_16x16x32_bf16(a, b, c, 0, 0, 0);
}

__device__ __forceinline__ f32x16 mfma32(bf16x8 a, bf16x8 b, f32x16 c) {
  return __builtin_amdgcn_mfma_f32_32x32x16_bf16(a, b, c, 0, 0, 0);
}

__device__ __forceinline__ void gload16(const void* g, void* lds) {
  __builtin_amdgcn_global_load_lds(
      (const __attribute__((address_space(1))) void*)g,
      (__attribute__((address_space(3))) void*)lds, 16, 0, 0);
}

__device__ __forceinline__ float quant1(float x, float scale, float qmax) {
  return rintf(fminf(fmaxf(x / scale, -qmax), qmax)) * scale;
}

// stage a 64x64 bf16 tile into LDS with a 128-thread block; XOR swizzle
// (chunk ^= row&7) applied on the GLOBAL source, LDS dest stays linear.
__device__ __forceinline__ void stage64b(const bf16* __restrict__ g, int rs, bf16* lds, int t) {
  #pragma unroll
  for (int r = 0; r < 4; r++) {
    const int cl  = r * 128 + t;           // 16B-chunk id in tile (512 total)
    const int row = cl >> 3;               // 8 chunks per 128B row
    const int scr = (cl & 7) ^ (row & 7);  // pre-swizzled source chunk
    gload16(g + (size_t)row * rs + scr * 8,
            (char*)lds + (size_t)(r * 128 + (t & 64)) * 16);
  }
}

// ---------- madd precompute + scalar-slot init ----------
__global__ __launch_bounds__(256) void k_prep(const float* __restrict__ mask,
                                              float* __restrict__ madd, float* __restrict__ scal) {
  constexpr float MSK2 = -14426.950408889634f;   // -10000 * log2(e)
  const int i = blockIdx.x * 256 + threadIdx.x;
  if (blockIdx.x == 0 && threadIdx.x < 32) scal[threadIdx.x] = 0.f;
  if (i < B_ * S_) madd[i] = (1.0f - mask[i]) * MSK2;
}

// ---------- fused per-tensor absmax + quant for the 6 weights ----------
struct WArgs {
  const float* w[6];
  bf16* q[6];
  size_t n4[6];
};

__global__ __launch_bounds__(256) void k_absmax6(WArgs a, float* __restrict__ slots) {
  const int z = blockIdx.z;
  const float* __restrict__ x = a.w[z];
  const size_t n4 = a.n4[z];
  size_t i = (size_t)blockIdx.x * 256 + threadIdx.x;
  const size_t stride = (size_t)gridDim.x * 256;
  float m = 0.f;
  for (; i < n4; i += stride) {
    float4 v = ((const float4*)x)[i];
    m = fmaxf(m, fmaxf(fmaxf(fabsf(v.x), fabsf(v.y)), fmaxf(fabsf(v.z), fabsf(v.w))));
  }
  #pragma unroll
  for (int o = 32; o; o >>= 1) m = fmaxf(m, __shfl_xor(m, o));
  __shared__ float red[4];
  if ((threadIdx.x & 63) == 0) red[threadIdx.x >> 6] = m;
  __syncthreads();
  if (threadIdx.x == 0)
    atomicMaxF(slots + z, fmaxf(fmaxf(red[0], red[1]), fmaxf(red[2], red[3])));
}

__global__ __launch_bounds__(256) void k_quant6(WArgs a, const float* __restrict__ slots,
                                                const int* __restrict__ bits) {
  const int z = blockIdx.z;
  const float* __restrict__ x = a.w[z];
  bf16* __restrict__ y = a.q[z];
  const size_t n4 = a.n4[z];
  const float qmax  = (float)((1 << (*bits - 1)) - 1);
  const float scale = fmaxf(slots[z], 1e-8f) / qmax;
  size_t i = (size_t)blockIdx.x * 256 + threadIdx.x;
  const size_t stride = (size_t)gridDim.x * 256;
  for (; i < n4; i += stride) {
    float4 v = ((const float4*)x)[i];
    bf16x4 o;
    o[0] = (bf16)quant1(v.x, scale, qmax);
    o[1] = (bf16)quant1(v.y, scale, qmax);
    o[2] = (bf16)quant1(v.z, scale, qmax);
    o[3] = (bf16)quant1(v.w, scale, qmax);
    ((bf16x4*)y)[i] = o;
  }
}

// ---------- fake-quant fp32 -> bf16 (activations) ----------
__global__ __launch_bounds__(256) void k_quant(const float* __restrict__ x, bf16* __restrict__ y,
                                               const float* __restrict__ slot,
                                               const int* __restrict__ bits, size_t n4) {
  const float qmax  = (float)((1 << (*bits - 1)) - 1);
  const float scale = fmaxf(*slot, 1e-8f) / qmax;
  size_t i = (size_t)blockIdx.x * 256 + threadIdx.x;
  const size_t stride = (size_t)gridDim.x * 256;
  for (; i < n4; i += stride) {
    float4 v = ((const float4*)x)[i];
    bf16x4 o;
    o[0] = (bf16)quant1(v.x, scale, qmax);
    o[1] = (bf16)quant1(v.y, scale, qmax);
    o[2] = (bf16)quant1(v.z, scale, qmax);
    o[3] = (bf16)quant1(v.w, scale, qmax);
    ((bf16x4*)y)[i] = o;
  }
}

// ---------- fake-quant bf16 in-place (GELU output) ----------
__global__ __launch_bounds__(256) void k_quant_ip(bf16* __restrict__ x,
                                                  const float* __restrict__ slot,
                                                  const int* __restrict__ bits, size_t n8) {
  const float qmax  = (float)((1 << (*bits - 1)) - 1);
  const float scale = fmaxf(*slot, 1e-8f) / qmax;
  size_t i = (size_t)blockIdx.x * 256 + threadIdx.x;
  if (i >= n8) return;
  bf16x8 v = ((const bf16x8*)x)[i];
  #pragma unroll
  for (int j = 0; j < 8; j++) v[j] = (bf16)quant1((float)v[j], scale, qmax);
  ((bf16x8*)x)[i] = v;
}

// ---------- LayerNorm (fp32 out, + absmax) : one block per row ----------
__global__ __launch_bounds__(256) void k_ln(const float* __restrict__ x, const float* __restrict__ g,
                                            const float* __restrict__ be, float* __restrict__ y,
                                            float* __restrict__ slot) {
  const int row = blockIdx.x, t = threadIdx.x;
  const float4 v = ((const float4*)(x + (size_t)row * D_))[t];
  float s = v.x + v.y + v.z + v.w;
  float q = v.x * v.x + v.y * v.y + v.z * v.z + v.w * v.w;
  #pragma unroll
  for (int o = 32; o; o >>= 1) { s += __shfl_xor(s, o); q += __shfl_xor(q, o); }
  __shared__ float red[8];
  const int wid = t >> 6;
  if ((t & 63) == 0) { red[wid] = s; red[4 + wid] = q; }
  __syncthreads();
  s = red[0] + red[1] + red[2] + red[3];
  q = red[4] + red[5] + red[6] + red[7];
  const float mean = s * (1.f / D_);
  const float rstd = rsqrtf(q * (1.f / D_) - mean * mean + 1e-5f);
  const float4 gv = ((const float4*)g)[t];
  const float4 bv = ((const float4*)be)[t];
  float4 o;
  o.x = (v.x - mean) * rstd * gv.x + bv.x;
  o.y = (v.y - mean) * rstd * gv.y + bv.y;
  o.z = (v.z - mean) * rstd * gv.z + bv.z;
  o.w = (v.w - mean) * rstd * gv.w + bv.w;
  ((float4*)(y + (size_t)row * D_))[t] = o;
  float m = fmaxf(fmaxf(fabsf(o.x), fabsf(o.y)), fmaxf(fabsf(o.z), fabsf(o.w)));
  #pragma unroll
  for (int oo = 32; oo; oo >>= 1) m = fmaxf(m, __shfl_xor(m, oo));
  __syncthreads();                 // red reuse
  if ((t & 63) == 0) red[wid] = m;
  __syncthreads();
  if (t == 0) atomicMaxF(slot, fmaxf(fmaxf(red[0], red[1]), fmaxf(red[2], red[3])));
}

// ---------- GEMM: C[M,N] = A[M,K] @ B[N,K]^T (+bias, +mode epilogue) ----------
// tile (MT*32)x128, BK=64, 4 waves in 2x2.  LDS rows are 128B with T2 chunk
// XOR-swizzle (chunk ^= row&7) applied on the GLOBAL source -> conflict-free
// ds_read_b128 per 8-lane group.  BK=64 halves barrier count vs BK=32.
struct GemmArgs {
  const bf16* A;
  const bf16* B0; const bf16* B1; const bf16* B2;
  const float* bias0; const float* bias1; const float* bias2;
  void* out0; void* out1; void* out2;
  const float* res;   // MODE 1: residual (fp32, same layout as out)
  float* slot;        // MODE 2: absmax slot
  int K; int ldc;
};

// MODE 0: bf16 out (+bias), 3-way select by blockIdx.z (QKV fused);
//         z==2 (V) stores TRANSPOSED: [b][col][s] for attention's PV B-operand
// MODE 1: f32 out = acc + bias + res
// MODE 2: bf16 out = gelu(acc+bias), absmax -> slot
template <int MODE, int MT>
__global__ __launch_bounds__(256) void k_gemm(GemmArgs a) {
  constexpr int TM = MT * 32;
  __shared__ __align__(16) bf16 As[TM * 64];
  __shared__ __align__(16) bf16 Bs[128 * 64];
  const int t = threadIdx.x, wid = t >> 6, lane = t & 63;
  const int grp = lane >> 4, l15 = lane & 15;
  const int wm = wid >> 1, wn = wid & 1;
  const size_t m0 = (size_t)blockIdx.x * TM, n0 = (size_t)blockIdx.y * 128;
  const int K = a.K, ldc = a.ldc;

  const bf16* Bw; const float* bias; void* outv;
  if constexpr (MODE == 0) {
    const int z = blockIdx.z;
    Bw   = z == 0 ? a.B0 : (z == 1 ? a.B1 : a.B2);
    bias = z == 0 ? a.bias0 : (z == 1 ? a.bias1 : a.bias2);
    outv = z == 0 ? a.out0 : (z == 1 ? a.out1 : a.out2);
  } else {
    Bw = a.B0; bias = a.bias0; outv = a.out0;
  }

  const f32x4 zero = {0.f, 0.f, 0.f, 0.f};
  f32x4 acc[MT][4];
  #pragma unroll
  for (int m = 0; m < MT; m++)
    #pragma unroll
    for (int n = 0; n < 4; n++) acc[m][n] = zero;

  for (int kt = 0; kt < K; kt += 64) {
    // stage A (TM*8 chunks -> MT rounds) and B (1024 chunks -> 4 rounds);
    // source chunk pre-swizzled, LDS dest linear (wave-uniform base + lane*16)
    #pragma unroll
    for (int r = 0; r < MT; r++) {
      const int cl = r * 256 + t;
      const int row = cl >> 3, c = cl & 7;
      gload16(a.A + (m0 + row) * (size_t)K + kt + ((c ^ (row & 7)) * 8),
              (char*)As + (size_t)(r * 256 + (t & 192)) * 16);
    }
    #pragma unroll
    for (int r = 0; r < 4; r++) {
      const int cl = r * 256 + t;
      const int row = cl >> 3, c = cl & 7;
      gload16(Bw + (n0 + row) * (size_t)K + kt + ((c ^ (row & 7)) * 8),
              (char*)Bs + (size_t)(r * 256 + (t & 192)) * 16);
    }
    __syncthreads();   // drains vmcnt (global_load_lds) + lgkm
    #pragma unroll
    for (int ks = 0; ks < 2; ks++) {
      bf16x8 bfv[4];
      #pragma unroll
      for (int n = 0; n < 4; n++) {
        const int rb = wn * 64 + n * 16 + l15;
        bfv[n] = *(const bf16x8*)(Bs + rb * 64 + (((ks * 4 + grp) ^ (rb & 7)) * 8));
      }
      #pragma unroll
      for (int m = 0; m < MT; m++) {
        const int ra = wm * (MT * 16) + m * 16 + l15;
        const bf16x8 af = *(const bf16x8*)(As + ra * 64 + (((ks * 4 + grp) ^ (ra & 7)) * 8));
        #pragma unroll
        for (int n = 0; n < 4; n++)
          acc[m][n] = mfma16(af, bfv[n], acc[m][n]);
      }
    }
    __syncthreads();   // protect LDS before next stage
  }

  // epilogue: C/D frag layout: row=(lane>>4)*4+i, col=lane&15
  const size_t gr0 = m0 + wm * (MT * 16) + grp * 4;
  const size_t gc0 = n0 + wn * 64 + l15;

  if constexpr (MODE == 0) {
    if (blockIdx.z == 2) {
      // V^T store: out[b][gc][s] packed bf16x4 along s (i dimension)
      #pragma unroll
      for (int n = 0; n < 4; n++) {
        const size_t gc = gc0 + n * 16;
        const float bc = bias[gc];
        #pragma unroll
        for (int m = 0; m < MT; m++) {
          const size_t gr = gr0 + m * 16;              // tokens gr..gr+3, same batch
          const size_t bb = gr >> 11, s0 = gr & (S_ - 1);
          bf16x4 vv;
          #pragma unroll
          for (int i = 0; i < 4; i++) vv[i] = (bf16)(acc[m][n][i] + bc);
          *(bf16x4*)((bf16*)outv + bb * (size_t)D_ * S_ + gc * S_ + s0) = vv;
        }
      }
      return;
    }
  }

  float lmax = 0.f;
  #pragma unroll
  for (int n = 0; n < 4; n++) {
    const size_t gc = gc0 + n * 16;
    const float bc = bias[gc];
    #pragma unroll
    for (int m = 0; m < MT; m++) {
      const size_t gr = gr0 + m * 16;
      #pragma unroll
      for (int i = 0; i < 4; i++) {
        const float v = acc[m][n][i] + bc;
        const size_t idx = (gr + i) * (size_t)ldc + gc;
        if constexpr (MODE == 0) {
          ((bf16*)outv)[idx] = (bf16)v;
        } else if constexpr (MODE == 1) {
          ((float*)outv)[idx] = v + a.res[idx];
        } else {
          const float gl = 0.5f * v * (1.0f + erff(v * 0.7071067811865475f));
          ((bf16*)outv)[idx] = (bf16)gl;
          lmax = fmaxf(lmax, fabsf(gl));
        }
      }
    }
  }
  if constexpr (MODE == 2) {
    #pragma unroll
    for (int o = 32; o; o >>= 1) lmax = fmaxf(lmax, __shfl_xor(lmax, o));
    __shared__ float red[4];
    if (lane == 0) red[wid] = lmax;
    __syncthreads();
    if (t == 0) atomicMaxF(a.slot, fmaxf(fmaxf(red[0], red[1]), fmaxf(red[2], red[3])));
  }
}

// ---------- fused attention (flash, swapped 32x32 MFMA, pipelined) ----------
// 2 waves x 32 q; KV tile 64.  Per iter i: {mv(i+1); stage K(i+2),V(i+1);
// PV(i); QK(i+1); softmax(i+1); barrier}.  PV(i)'s MFMAs overlap softmax(i+1)
// VALU; stages get the whole body (~1300cy) to land before the barrier drain.
// Buffer lifetimes: K(i+2)->buf[i&1] (K(i) freed at iter i-1 barrier);
// V(i+1)->buf[(i+1)&1] (V(i-1) freed).  Softmax is in-register (swapped QK),
// tree max (max3-fusable), defer-max (T13), cvt_pk+permlane pack (T12).
__global__ __launch_bounds__(128) void k_attn(const bf16* __restrict__ qb, const bf16* __restrict__ kb,
                                              const bf16* __restrict__ vt, const float* __restrict__ madd,
                                              float* __restrict__ out, float* __restrict__ slot) {
  constexpr float SCL2 = 0.18033688011112042f;   // 0.125 * log2(e)  (exp2 domain)
  constexpr float THR  = 8.0f;                   // defer-max threshold (log2 units)
  constexpr int NTILE  = S_ / 64;                // 32
  __shared__ __align__(16) bf16 Ks[2][64 * 64];  // [buf][key][d]  (chunk-swizzled)
  __shared__ __align__(16) bf16 Vs[2][64 * 64];  // [buf][d][key]  (chunk-swizzled)
  __shared__ float red[2];
  const int t = threadIdx.x, wid = t >> 6, lane = t & 63;
  const int l31 = lane & 31, hi = lane >> 5;
  const int b = blockIdx.y >> 4, h = blockIdx.y & 15;   // H = 16
  const size_t qkbase = ((size_t)b * S_) * D_ + (size_t)h * HD_;
  const size_t vtbase = (size_t)b * D_ * S_ + (size_t)h * HD_ * S_;
  const int q = blockIdx.x * 64 + wid * 32 + l31;       // this lane's q-row

  // Q fragments: B-operand of mfma(K,Q): col=q (lane-local)
  bf16x8 qf[4];
  #pragma unroll
  for (int j = 0; j < 4; j++)
    qf[j] = *(const bf16x8*)(qb + qkbase + (size_t)q * D_ + j * 16 + hi * 8);

  f32x16 ao0, ao1;
  #pragma unroll
  for (int r = 0; r < 16; r++) { ao0[r] = 0.f; ao1[r] = 0.f; }
  float mi = -INFINITY, li = 0.f;
  unsigned pk[16];
  f32x4 mv[2][4];
  const float* mp = madd + (size_t)b * S_ + hi * 4;
  const int xk = (l31 & 7);   // read-side chunk XOR (row = l31 / 32+l31)

  // QK^T + softmax + pack for tile given K buffer; updates mi/li/ao/pk
  auto qk_softmax = [&](const bf16* Kb) {
    f32x16 s0, s1;
    #pragma unroll
    for (int r = 0; r < 16; r++) { s0[r] = 0.f; s1[r] = 0.f; }
    #pragma unroll
    for (int j = 0; j < 4; j++) {
      const int ch = j * 2 + hi;
      const bf16x8 kf0 = *(const bf16x8*)(Kb + l31 * 64 + (ch ^ xk) * 8);
      const bf16x8 kf1 = *(const bf16x8*)(Kb + (32 + l31) * 64 + (ch ^ xk) * 8);
      s0 = mfma32(kf0, qf[j], s0);
      s1 = mfma32(kf1, qf[j], s1);
    }
    float pv_[32];
    #pragma unroll
    for (int r = 0; r < 16; r++) pv_[r]      = s0[r] * SCL2 + mv[0][r >> 2][r & 3];
    #pragma unroll
    for (int r = 0; r < 16; r++) pv_[16 + r] = s1[r] * SCL2 + mv[1][r >> 2][r & 3];
    // tree max (depth 5, ILP-friendly; fmaxf pairs fuse to max3)
    float m16[16];
    #pragma unroll
    for (int r = 0; r < 16; r++) m16[r] = fmaxf(pv_[r], pv_[16 + r]);
    #pragma unroll
    for (int r = 0; r < 8; r++) m16[r] = fmaxf(m16[r], m16[8 + r]);
    #pragma unroll
    for (int r = 0; r < 4; r++) m16[r] = fmaxf(m16[r], m16[4 + r]);
    float mx = fmaxf(fmaxf(m16[0], m16[1]), fmaxf(m16[2], m16[3]));
    mx = fmaxf(mx, __shfl_xor(mx, 32));
    if (!__all(mx - mi <= THR)) {        // defer-max: rescale only when needed
      const float mnew = fmaxf(mi, mx);
      const float co = exp2f(mi - mnew);
      li *= co;
      #pragma unroll
      for (int r = 0; r < 16; r++) { ao0[r] *= co; ao1[r] *= co; }
      mi = mnew;
    }
    #pragma unroll
    for (int r = 0; r < 32; r++) pv_[r] = exp2f(pv_[r] - mi);
    // tree sum
    float sm[16];
    #pragma unroll
    for (int r = 0; r < 16; r++) sm[r] = pv_[r] + pv_[16 + r];
    #pragma unroll
    for (int r = 0; r < 8; r++) sm[r] += sm[8 + r];
    #pragma unroll
    for (int r = 0; r < 4; r++) sm[r] += sm[4 + r];
    li += (sm[0] + sm[1]) + (sm[2] + sm[3]);
    // pack P -> PV B-operand frags (cvt_pk + permlane32_swap)
    #pragma unroll
    for (int tt = 0; tt < 8; tt++) {
      asm("v_cvt_pk_bf16_f32 %0, %1, %2" : "=v"(pk[tt])     : "v"(pv_[2 * tt]),      "v"(pv_[2 * tt + 1]));
      asm("v_cvt_pk_bf16_f32 %0, %1, %2" : "=v"(pk[8 + tt]) : "v"(pv_[16 + 2 * tt]), "v"(pv_[16 + 2 * tt + 1]));
    }
    #pragma unroll
    for (int g = 0; g < 4; g++) {
      asm volatile("v_permlane32_swap_b32 %0, %1" : "+v"(pk[4 * g]),     "+v"(pk[4 * g + 2]));
      asm volatile("v_permlane32_swap_b32 %0, %1" : "+v"(pk[4 * g + 1]), "+v"(pk[4 * g + 3]));
    }
  };

  auto pv_accum = [&](const bf16* Vb) {
    #pragma unroll
    for (int j = 0; j < 4; j++) {
      const u32x4 w = {pk[4 * j], pk[4 * j + 1], pk[4 * j + 2], pk[4 * j + 3]};
      const bf16x8 pf = __builtin_bit_cast(bf16x8, w);
      const int ch = j * 2 + hi;
      const bf16x8 vf0 = *(const bf16x8*)(Vb + l31 * 64 + (ch ^ xk) * 8);
      const bf16x8 vf1 = *(const bf16x8*)(Vb + (32 + l31) * 64 + (ch ^ xk) * 8);
      ao0 = mfma32(vf0, pf, ao0);
      ao1 = mfma32(vf1, pf, ao1);
    }
  };

  // ---- prologue: mv(0); stage K0,V0,K1; QK(0)+softmax(0) ----
  #pragma unroll
  for (int kb2 = 0; kb2 < 2; kb2++)
    #pragma unroll
    for (int g = 0; g < 4; g++) mv[kb2][g] = *(const f32x4*)(mp + kb2 * 32 + g * 8);
  __builtin_amdgcn_sched_barrier(0);
  stage64b(kb + qkbase, D_, Ks[0], t);
  stage64b(vt + vtbase, S_, Vs[0], t);
  stage64b(kb + qkbase + (size_t)64 * D_, D_, Ks[1], t);
  __syncthreads();
  qk_softmax(Ks[0]);
  __syncthreads();      // all waves done with Ks[0] before iter0 stages K2->Ks[0]

  // ---- main loop ----
  for (int i = 0; i < NTILE; i++) {
    const int cur = i & 1;
    const bool last = (i == NTILE - 1);
    if (!last) {
      const int kt1 = (i + 1) * 64;
      #pragma unroll
      for (int kb2 = 0; kb2 < 2; kb2++)
        #pragma unroll
        for (int g = 0; g < 4; g++) mv[kb2][g] = *(const f32x4*)(mp + kt1 + kb2 * 32 + g * 8);
      __builtin_amdgcn_sched_barrier(0);
      if (i + 2 < NTILE) stage64b(kb + qkbase + (size_t)(i + 2) * 64 * D_, D_, Ks[cur], t);
      stage64b(vt + vtbase + (i + 1) * 64, S_, Vs[cur ^ 1], t);
    }
    pv_accum(Vs[cur]);                 // tile i (pk from previous softmax)
    if (!last) {
      qk_softmax(Ks[cur ^ 1]);         // tile i+1
      __syncthreads();                 // stages landed; buffers rotate
    }
  }

  // epilogue: join the hi-pair's li, normalize, write fp32, absmax
  li += __shfl_xor(li, 32);
  const float invl = 1.0f / li;
  float lmax = 0.f;
  float* orow = out + qkbase + (size_t)q * D_;
  #pragma unroll
  for (int db2 = 0; db2 < 2; db2++) {
    #pragma unroll
    for (int rg = 0; rg < 4; rg++) {
      float4 o;
      o.x = (db2 ? ao1[rg * 4 + 0] : ao0[rg * 4 + 0]) * invl;
      o.y = (db2 ? ao1[rg * 4 + 1] : ao0[rg * 4 + 1]) * invl;
      o.z = (db2 ? ao1[rg * 4 + 2] : ao0[rg * 4 + 2]) * invl;
      o.w = (db2 ? ao1[rg * 4 + 3] : ao0[rg * 4 + 3]) * invl;
      *(float4*)(orow + db2 * 32 + rg * 8 + hi * 4) = o;
      lmax = fmaxf(lmax, fmaxf(fmaxf(fabsf(o.x), fabsf(o.y)), fmaxf(fabsf(o.z), fabsf(o.w))));
    }
  }
  #pragma unroll
  for (int o = 32; o; o >>= 1) lmax = fmaxf(lmax, __shfl_xor(lmax, o));
  if (lane == 0) red[wid] = lmax;
  __syncthreads();
  if (t == 0) atomicMaxF(slot, fmaxf(red[0], red[1]));
}

// ---------- launch ----------
extern "C" void kernel_launch(void* const* d_in, const int* in_sizes, int n_in,
                              void* d_out, int out_size, void* d_ws, size_t ws_size,
                              hipStream_t stream) {
  const float* hs   = (const float*)d_in[0];
  const float* mask = (const float*)d_in[1];
  const float* wq = (const float*)d_in[2];  const float* bq = (const float*)d_in[3];
  const float* wk = (const float*)d_in[4];  const float* bk = (const float*)d_in[5];
  const float* wv = (const float*)d_in[6];  const float* bv = (const float*)d_in[7];
  const float* wo = (const float*)d_in[8];  const float* bo = (const float*)d_in[9];
  const float* w1 = (const float*)d_in[10]; const float* b1 = (const float*)d_in[11];
  const float* w2 = (const float*)d_in[12]; const float* b2 = (const float*)d_in[13];
  const float* g1 = (const float*)d_in[14]; const float* be1 = (const float*)d_in[15];
  const float* g2 = (const float*)d_in[16]; const float* be2 = (const float*)d_in[17];
  const int* wbits = (const int*)d_in[18];
  const int* abits = (const int*)d_in[19];

  // workspace layout (bytes)
  char* ws = (char*)d_ws;
  size_t off = 0;
  float* scal = (float*)ws;                      off += 256;        // absmax slots
  float* maddg= (float*)(ws + off);              off += (size_t)NT * 4;       // (1-mask)*MSK2
  float* fbuf = (float*)(ws + off);              off += (size_t)NT * D_ * 4;  // x1f/attnf/x2f
  bf16*  qx   = (bf16*)(ws + off);               off += (size_t)NT * D_ * 2;  // x1q/attnq/x2q
  bf16*  qb   = (bf16*)(ws + off);               off += (size_t)NT * D_ * 2;
  bf16*  kbuf = (bf16*)(ws + off);               off += (size_t)NT * D_ * 2;
  bf16*  vbuf = (bf16*)(ws + off);               off += (size_t)NT * D_ * 2;  // holds V^T
  float* h2   = (float*)(ws + off);              off += (size_t)NT * D_ * 4;  // attn residual out
  bf16*  h1   = (bf16*)(ws + off);               off += (size_t)NT * I_ * 2;  // gelu out (quant ip)
  bf16*  wqq  = (bf16*)(ws + off);               off += (size_t)D_ * D_ * 2;
  bf16*  wkq  = (bf16*)(ws + off);               off += (size_t)D_ * D_ * 2;
  bf16*  wvq  = (bf16*)(ws + off);               off += (size_t)D_ * D_ * 2;
  bf16*  woq  = (bf16*)(ws + off);               off += (size_t)D_ * D_ * 2;
  bf16*  w1q  = (bf16*)(ws + off);               off += (size_t)I_ * D_ * 2;
  bf16*  w2q  = (bf16*)(ws + off);               off += (size_t)D_ * I_ * 2;
  if (ws_size < off) return;  // insufficient workspace: fail cleanly

  // slots: 0 x1, 1 attn, 2 x2, 3 h1, 4..9 weights
  k_prep<<<NT / 256, 256, 0, stream>>>(mask, maddg, scal);

  const size_t nDD4 = (size_t)D_ * D_ / 4, nDI4 = (size_t)D_ * I_ / 4;
  WArgs wa;
  wa.w[0] = wq; wa.w[1] = wk; wa.w[2] = wv; wa.w[3] = wo; wa.w[4] = w1; wa.w[5] = w2;
  wa.q[0] = wqq; wa.q[1] = wkq; wa.q[2] = wvq; wa.q[3] = woq; wa.q[4] = w1q; wa.q[5] = w2q;
  wa.n4[0] = nDD4; wa.n4[1] = nDD4; wa.n4[2] = nDD4; wa.n4[3] = nDD4;
  wa.n4[4] = nDI4; wa.n4[5] = nDI4;
  k_absmax6<<<dim3(1024, 1, 6), 256, 0, stream>>>(wa, scal + 4);
  k_quant6<<<dim3(1024, 1, 6), 256, 0, stream>>>(wa, scal + 4, wbits);

  const size_t nND4 = (size_t)NT * D_ / 4;

  // LN1 -> fake-quant -> fused QKV GEMM (V written transposed)
  k_ln<<<NT, 256, 0, stream>>>(hs, g1, be1, fbuf, scal + 0);
  k_quant<<<2048, 256, 0, stream>>>(fbuf, qx, scal + 0, abits, nND4);
  {
    GemmArgs ga{};
    ga.A = qx; ga.B0 = wqq; ga.B1 = wkq; ga.B2 = wvq;
    ga.bias0 = bq; ga.bias1 = bk; ga.bias2 = bv;
    ga.out0 = qb; ga.out1 = kbuf; ga.out2 = vbuf;
    ga.K = D_; ga.ldc = D_;
    k_gemm<0, 4><<<dim3(NT / 128, D_ / 128, 3), 256, 0, stream>>>(ga);
  }

  // attention -> fake-quant -> out-proj (+residual)
  k_attn<<<dim3(S_ / 64, B_ * H_), 128, 0, stream>>>(qb, kbuf, vbuf, maddg, fbuf, scal + 1);
  k_quant<<<2048, 256, 0, stream>>>(fbuf, qx, scal + 1, abits, nND4);
  {
    GemmArgs ga{};
    ga.A = qx; ga.B0 = woq; ga.bias0 = bo; ga.out0 = h2; ga.res = hs;
    ga.K = D_; ga.ldc = D_;
    k_gemm<1, 2><<<dim3(NT / 64, D_ / 128), 256, 0, stream>>>(ga);
  }

  // LN2 -> fake-quant -> MLP1 (gelu + absmax) -> fake-quant -> MLP2 (+residual)
  k_ln<<<NT, 256, 0, stream>>>(h2, g2, be2, fbuf, scal + 2);
  k_quant<<<2048, 256, 0, stream>>>(fbuf, qx, scal + 2, abits, nND4);
  {
    GemmArgs ga{};
    ga.A = qx; ga.B0 = w1q; ga.bias0 = b1; ga.out0 = h1; ga.slot = scal + 3;
    ga.K = D_; ga.ldc = I_;
    k_gemm<2, 4><<<dim3(NT / 128, I_ / 128), 256, 0, stream>>>(ga);
  }
  k_quant_ip<<<(NT * (size_t)I_ / 8 + 255) / 256, 256, 0, stream>>>(h1, scal + 3, abits,
                                                                    (size_t)NT * I_ / 8);
  {
    GemmArgs ga{};
    ga.A = h1; ga.B0 = w2q; ga.bias0 = b2; ga.out0 = d_out; ga.res = h2;
    ga.K = I_; ga.ldc = D_;
    k_gemm<1, 2><<<dim3(NT / 64, D_ / 128), 256, 0, stream>>>(ga);
  }
}

// Round 7
// 493.751 us; speedup vs baseline: 1.6082x; 1.0027x over previous
//
#include <hip/hip_runtime.h>
#include <hip/hip_bf16.h>
#include <math.h>

typedef __bf16 bf16;
typedef __bf16 bf16x8 __attribute__((ext_vector_type(8)));
typedef __bf16 bf16x4 __attribute__((ext_vector_type(4)));
typedef float  f32x4  __attribute__((ext_vector_type(4)));
typedef float  f32x16 __attribute__((ext_vector_type(16)));
typedef unsigned int u32x4 __attribute__((ext_vector_type(4)));

static constexpr int B_  = 2;
static constexpr int S_  = 2048;
static constexpr int D_  = 1024;
static constexpr int H_  = 16;
static constexpr int HD_ = 64;
static constexpr int I_  = 4096;
static constexpr int NT  = B_ * S_;       // 4096 tokens

// ---------- helpers ----------
__device__ __forceinline__ void atomicMaxF(float* p, float v) {
  atomicMax((unsigned int*)p, __float_as_uint(v));   // v >= 0 always
}

__device__ __forceinline__ f32x4 mfma16(bf16x8 a, bf16x8 b, f32x4 c) {
  return __builtin_amdgcn_mfma_f32_16x16x32_bf16(a, b, c, 0, 0, 0);
}

__device__ __forceinline__ f32x16 mfma32(bf16x8 a, bf16x8 b, f32x16 c) {
  return __builtin_amdgcn_mfma_f32_32x32x16_bf16(a, b, c, 0, 0, 0);
}

__device__ __forceinline__ void gload16(const void* g, void* lds) {
  __builtin_amdgcn_global_load_lds(
      (const __attribute__((address_space(1))) void*)g,
      (__attribute__((address_space(3))) void*)lds, 16, 0, 0);
}

__device__ __forceinline__ float quant1(float x, float scale, float qmax) {
  return rintf(fminf(fmaxf(x / scale, -qmax), qmax)) * scale;
}

// stage a 64x64 bf16 tile into LDS with a 128-thread block; XOR swizzle
// (chunk ^= row&7) applied on the GLOBAL source, LDS dest stays linear.
__device__ __forceinline__ void stage64b(const bf16* __restrict__ g, int rs, bf16* lds, int t) {
  #pragma unroll
  for (int r = 0; r < 4; r++) {
    const int cl  = r * 128 + t;           // 16B-chunk id in tile (512 total)
    const int row = cl >> 3;               // 8 chunks per 128B row
    const int scr = (cl & 7) ^ (row & 7);  // pre-swizzled source chunk
    gload16(g + (size_t)row * rs + scr * 8,
            (char*)lds + (size_t)(r * 128 + (t & 64)) * 16);
  }
}

// ---------- scalar-slot init (must precede k_prep's atomics) ----------
__global__ void k_init(float* s) {
  if (threadIdx.x < 32) s[threadIdx.x] = 0.f;
}

// ---------- madd precompute + mask-nontrivial flag (scal[10]) ----------
__global__ __launch_bounds__(256) void k_prep(const float* __restrict__ mask,
                                              float* __restrict__ madd, float* __restrict__ scal) {
  constexpr float MSK2 = -14426.950408889634f;   // -10000 * log2(e)
  const int i = blockIdx.x * 256 + threadIdx.x;
  if (i < B_ * S_) {
    const float mv = (1.0f - mask[i]) * MSK2;
    madd[i] = mv;
    float nz = fabsf(mv);
    #pragma unroll
    for (int o = 32; o; o >>= 1) nz = fmaxf(nz, __shfl_xor(nz, o));
    if ((threadIdx.x & 63) == 0 && nz > 0.f) atomicMaxF(scal + 10, nz);
  }
}

// ---------- fused per-tensor absmax + quant for the 6 weights ----------
struct WArgs {
  const float* w[6];
  bf16* q[6];
  size_t n4[6];
};

__global__ __launch_bounds__(256) void k_absmax6(WArgs a, float* __restrict__ slots) {
  const int z = blockIdx.z;
  const float* __restrict__ x = a.w[z];
  const size_t n4 = a.n4[z];
  size_t i = (size_t)blockIdx.x * 256 + threadIdx.x;
  const size_t stride = (size_t)gridDim.x * 256;
  float m = 0.f;
  for (; i < n4; i += stride) {
    float4 v = ((const float4*)x)[i];
    m = fmaxf(m, fmaxf(fmaxf(fabsf(v.x), fabsf(v.y)), fmaxf(fabsf(v.z), fabsf(v.w))));
  }
  #pragma unroll
  for (int o = 32; o; o >>= 1) m = fmaxf(m, __shfl_xor(m, o));
  __shared__ float red[4];
  if ((threadIdx.x & 63) == 0) red[threadIdx.x >> 6] = m;
  __syncthreads();
  if (threadIdx.x == 0)
    atomicMaxF(slots + z, fmaxf(fmaxf(red[0], red[1]), fmaxf(red[2], red[3])));
}

__global__ __launch_bounds__(256) void k_quant6(WArgs a, const float* __restrict__ slots,
                                                const int* __restrict__ bits) {
  const int z = blockIdx.z;
  const float* __restrict__ x = a.w[z];
  bf16* __restrict__ y = a.q[z];
  const size_t n4 = a.n4[z];
  const float qmax  = (float)((1 << (*bits - 1)) - 1);
  const float scale = fmaxf(slots[z], 1e-8f) / qmax;
  size_t i = (size_t)blockIdx.x * 256 + threadIdx.x;
  const size_t stride = (size_t)gridDim.x * 256;
  for (; i < n4; i += stride) {
    float4 v = ((const float4*)x)[i];
    bf16x4 o;
    o[0] = (bf16)quant1(v.x, scale, qmax);
    o[1] = (bf16)quant1(v.y, scale, qmax);
    o[2] = (bf16)quant1(v.z, scale, qmax);
    o[3] = (bf16)quant1(v.w, scale, qmax);
    ((bf16x4*)y)[i] = o;
  }
}

// ---------- fake-quant fp32 -> bf16 (activations) ----------
__global__ __launch_bounds__(256) void k_quant(const float* __restrict__ x, bf16* __restrict__ y,
                                               const float* __restrict__ slot,
                                               const int* __restrict__ bits, size_t n4) {
  const float qmax  = (float)((1 << (*bits - 1)) - 1);
  const float scale = fmaxf(*slot, 1e-8f) / qmax;
  size_t i = (size_t)blockIdx.x * 256 + threadIdx.x;
  const size_t stride = (size_t)gridDim.x * 256;
  for (; i < n4; i += stride) {
    float4 v = ((const float4*)x)[i];
    bf16x4 o;
    o[0] = (bf16)quant1(v.x, scale, qmax);
    o[1] = (bf16)quant1(v.y, scale, qmax);
    o[2] = (bf16)quant1(v.z, scale, qmax);
    o[3] = (bf16)quant1(v.w, scale, qmax);
    ((bf16x4*)y)[i] = o;
  }
}

// ---------- fake-quant bf16 in-place (GELU output) ----------
__global__ __launch_bounds__(256) void k_quant_ip(bf16* __restrict__ x,
                                                  const float* __restrict__ slot,
                                                  const int* __restrict__ bits, size_t n8) {
  const float qmax  = (float)((1 << (*bits - 1)) - 1);
  const float scale = fmaxf(*slot, 1e-8f) / qmax;
  size_t i = (size_t)blockIdx.x * 256 + threadIdx.x;
  if (i >= n8) return;
  bf16x8 v = ((const bf16x8*)x)[i];
  #pragma unroll
  for (int j = 0; j < 8; j++) v[j] = (bf16)quant1((float)v[j], scale, qmax);
  ((bf16x8*)x)[i] = v;
}

// ---------- LayerNorm (fp32 out, + absmax) : one block per row ----------
__global__ __launch_bounds__(256) void k_ln(const float* __restrict__ x, const float* __restrict__ g,
                                            const float* __restrict__ be, float* __restrict__ y,
                                            float* __restrict__ slot) {
  const int row = blockIdx.x, t = threadIdx.x;
  const float4 v = ((const float4*)(x + (size_t)row * D_))[t];
  float s = v.x + v.y + v.z + v.w;
  float q = v.x * v.x + v.y * v.y + v.z * v.z + v.w * v.w;
  #pragma unroll
  for (int o = 32; o; o >>= 1) { s += __shfl_xor(s, o); q += __shfl_xor(q, o); }
  __shared__ float red[8];
  const int wid = t >> 6;
  if ((t & 63) == 0) { red[wid] = s; red[4 + wid] = q; }
  __syncthreads();
  s = red[0] + red[1] + red[2] + red[3];
  q = red[4] + red[5] + red[6] + red[7];
  const float mean = s * (1.f / D_);
  const float rstd = rsqrtf(q * (1.f / D_) - mean * mean + 1e-5f);
  const float4 gv = ((const float4*)g)[t];
  const float4 bv = ((const float4*)be)[t];
  float4 o;
  o.x = (v.x - mean) * rstd * gv.x + bv.x;
  o.y = (v.y - mean) * rstd * gv.y + bv.y;
  o.z = (v.z - mean) * rstd * gv.z + bv.z;
  o.w = (v.w - mean) * rstd * gv.w + bv.w;
  ((float4*)(y + (size_t)row * D_))[t] = o;
  float m = fmaxf(fmaxf(fabsf(o.x), fabsf(o.y)), fmaxf(fabsf(o.z), fabsf(o.w)));
  #pragma unroll
  for (int oo = 32; oo; oo >>= 1) m = fmaxf(m, __shfl_xor(m, oo));
  __syncthreads();                 // red reuse
  if ((t & 63) == 0) red[wid] = m;
  __syncthreads();
  if (t == 0) atomicMaxF(slot, fmaxf(fmaxf(red[0], red[1]), fmaxf(red[2], red[3])));
}

// ---------- GEMM: C[M,N] = A[M,K] @ B[N,K]^T (+bias, +mode epilogue) ----------
// tile (MT*32)x128, BK=64, 4 waves in 2x2.  T3-minimum 2-phase: double-buffered
// LDS, stage(t+1) issued BEFORE compute(t), ONE barrier per k-step — the
// prefetch gets the whole MFMA phase to land instead of a mid-step drain.
// T2 chunk XOR-swizzle (chunk ^= row&7) on the GLOBAL source, LDS linear.
struct GemmArgs {
  const bf16* A;
  const bf16* B0; const bf16* B1; const bf16* B2;
  const float* bias0; const float* bias1; const float* bias2;
  void* out0; void* out1; void* out2;
  const float* res;   // MODE 1: residual (fp32, same layout as out)
  float* slot;        // MODE 2: absmax slot
  int K; int ldc;
};

// MODE 0: bf16 out (+bias), 3-way select by blockIdx.z (QKV fused);
//         z==2 (V) stores TRANSPOSED: [b][col][s] for attention's PV B-operand
// MODE 1: f32 out = acc + bias + res
// MODE 2: bf16 out = gelu(acc+bias), absmax -> slot
template <int MODE, int MT>
__global__ __launch_bounds__(256) void k_gemm(GemmArgs a) {
  constexpr int TM = MT * 32;
  __shared__ __align__(16) bf16 As[2][TM * 64];    // MT=4: 2x16KB
  __shared__ __align__(16) bf16 Bs[2][128 * 64];   // 2x16KB
  const int t = threadIdx.x, wid = t >> 6, lane = t & 63;
  const int grp = lane >> 4, l15 = lane & 15;
  const int wm = wid >> 1, wn = wid & 1;
  const size_t m0 = (size_t)blockIdx.x * TM, n0 = (size_t)blockIdx.y * 128;
  const int K = a.K, ldc = a.ldc;

  const bf16* Bw; const float* bias; void* outv;
  if constexpr (MODE == 0) {
    const int z = blockIdx.z;
    Bw   = z == 0 ? a.B0 : (z == 1 ? a.B1 : a.B2);
    bias = z == 0 ? a.bias0 : (z == 1 ? a.bias1 : a.bias2);
    outv = z == 0 ? a.out0 : (z == 1 ? a.out1 : a.out2);
  } else {
    Bw = a.B0; bias = a.bias0; outv = a.out0;
  }

  const f32x4 zero = {0.f, 0.f, 0.f, 0.f};
  f32x4 acc[MT][4];
  #pragma unroll
  for (int m = 0; m < MT; m++)
    #pragma unroll
    for (int n = 0; n < 4; n++) acc[m][n] = zero;

  auto stage = [&](int kt, int buf) {
    #pragma unroll
    for (int r = 0; r < MT; r++) {
      const int cl = r * 256 + t;
      const int row = cl >> 3, c = cl & 7;
      gload16(a.A + (m0 + row) * (size_t)K + kt + ((c ^ (row & 7)) * 8),
              (char*)&As[buf][0] + (size_t)(r * 256 + (t & 192)) * 16);
    }
    #pragma unroll
    for (int r = 0; r < 4; r++) {
      const int cl = r * 256 + t;
      const int row = cl >> 3, c = cl & 7;
      gload16(Bw + (n0 + row) * (size_t)K + kt + ((c ^ (row & 7)) * 8),
              (char*)&Bs[buf][0] + (size_t)(r * 256 + (t & 192)) * 16);
    }
  };

  stage(0, 0);
  __syncthreads();           // tile 0 resident
  int cur = 0;
  for (int kt = 0; kt < K; kt += 64) {
    if (kt + 64 < K) stage(kt + 64, cur ^ 1);   // prefetch next (covered by MFMA)
    #pragma unroll
    for (int ks = 0; ks < 2; ks++) {
      bf16x8 bfv[4];
      #pragma unroll
      for (int n = 0; n < 4; n++) {
        const int rb = wn * 64 + n * 16 + l15;
        bfv[n] = *(const bf16x8*)(&Bs[cur][0] + rb * 64 + (((ks * 4 + grp) ^ (rb & 7)) * 8));
      }
      #pragma unroll
      for (int m = 0; m < MT; m++) {
        const int ra = wm * (MT * 16) + m * 16 + l15;
        const bf16x8 af = *(const bf16x8*)(&As[cur][0] + ra * 64 + (((ks * 4 + grp) ^ (ra & 7)) * 8));
        #pragma unroll
        for (int n = 0; n < 4; n++)
          acc[m][n] = mfma16(af, bfv[n], acc[m][n]);
      }
    }
    __syncthreads();         // drains prefetch (vmcnt) + protects cur for rotate
    cur ^= 1;
  }

  // epilogue: C/D frag layout: row=(lane>>4)*4+i, col=lane&15
  const size_t gr0 = m0 + wm * (MT * 16) + grp * 4;
  const size_t gc0 = n0 + wn * 64 + l15;

  if constexpr (MODE == 0) {
    if (blockIdx.z == 2) {
      // V^T store: out[b][gc][s] packed bf16x4 along s (i dimension)
      #pragma unroll
      for (int n = 0; n < 4; n++) {
        const size_t gc = gc0 + n * 16;
        const float bc = bias[gc];
        #pragma unroll
        for (int m = 0; m < MT; m++) {
          const size_t gr = gr0 + m * 16;              // tokens gr..gr+3, same batch
          const size_t bb = gr >> 11, s0 = gr & (S_ - 1);
          bf16x4 vv;
          #pragma unroll
          for (int i = 0; i < 4; i++) vv[i] = (bf16)(acc[m][n][i] + bc);
          *(bf16x4*)((bf16*)outv + bb * (size_t)D_ * S_ + gc * S_ + s0) = vv;
        }
      }
      return;
    }
  }

  float lmax = 0.f;
  #pragma unroll
  for (int n = 0; n < 4; n++) {
    const size_t gc = gc0 + n * 16;
    const float bc = bias[gc];
    #pragma unroll
    for (int m = 0; m < MT; m++) {
      const size_t gr = gr0 + m * 16;
      #pragma unroll
      for (int i = 0; i < 4; i++) {
        const float v = acc[m][n][i] + bc;
        const size_t idx = (gr + i) * (size_t)ldc + gc;
        if constexpr (MODE == 0) {
          ((bf16*)outv)[idx] = (bf16)v;
        } else if constexpr (MODE == 1) {
          ((float*)outv)[idx] = v + a.res[idx];
        } else {
          const float gl = 0.5f * v * (1.0f + erff(v * 0.7071067811865475f));
          ((bf16*)outv)[idx] = (bf16)gl;
          lmax = fmaxf(lmax, fabsf(gl));
        }
      }
    }
  }
  if constexpr (MODE == 2) {
    #pragma unroll
    for (int o = 32; o; o >>= 1) lmax = fmaxf(lmax, __shfl_xor(lmax, o));
    float* red = (float*)&As[0][0];     // LDS reuse (k-loop done; stay <=64KB)
    if (lane == 0) red[wid] = lmax;
    __syncthreads();
    if (t == 0) atomicMaxF(a.slot, fmaxf(fmaxf(red[0], red[1]), fmaxf(red[2], red[3])));
  }
}

// ---------- fused attention (flash, swapped 32x32 MFMA) ----------
// 2 waves x 32 q; KV tile 64, double-buffered; stage(i+1) before compute(i),
// one barrier per tile.  Swapped QK (mfma(K,Q)) -> scores lane-local; softmax
// in-register with tree max/sum, defer-max (T13), cvt_pk+permlane pack (T12).
// Uniform fast path when mask is trivial (scal[10]==0): no mask loads, max in
// RAW score domain, exp via single fma+exp2 (saves ~25% VALU/tile).
__global__ __launch_bounds__(128) void k_attn(const bf16* __restrict__ qb, const bf16* __restrict__ kb,
                                              const bf16* __restrict__ vt, const float* __restrict__ madd,
                                              float* __restrict__ out, float* __restrict__ scal) {
  constexpr float SCL2 = 0.18033688011112042f;   // 0.125 * log2(e)
  constexpr float THR  = 8.0f;                   // defer-max threshold (log2 units)
  constexpr float THRR = THR / SCL2;             // same, raw-score units
  constexpr int NTILE  = S_ / 64;                // 32
  __shared__ __align__(16) bf16 Ks[2][64 * 64];  // [buf][key][d]  (chunk-swizzled)
  __shared__ __align__(16) bf16 Vs[2][64 * 64];  // [buf][d][key]  (chunk-swizzled)
  __shared__ float red[2];
  const int t = threadIdx.x, wid = t >> 6, lane = t & 63;
  const int l31 = lane & 31, hi = lane >> 5;
  const int b = blockIdx.y >> 4, h = blockIdx.y & 15;   // H = 16
  const size_t qkbase = ((size_t)b * S_) * D_ + (size_t)h * HD_;
  const size_t vtbase = (size_t)b * D_ * S_ + (size_t)h * HD_ * S_;
  const int q = blockIdx.x * 64 + wid * 32 + l31;       // this lane's q-row
  const bool nomask = (scal[10] == 0.0f);               // uniform scalar branch

  bf16x8 qf[4];
  #pragma unroll
  for (int j = 0; j < 4; j++)
    qf[j] = *(const bf16x8*)(qb + qkbase + (size_t)q * D_ + j * 16 + hi * 8);

  f32x16 ao0, ao1;
  #pragma unroll
  for (int r = 0; r < 16; r++) { ao0[r] = 0.f; ao1[r] = 0.f; }
  float mi = -INFINITY, li = 0.f;       // mi: raw units (fast) or log2 units (slow)
  const float* mp = madd + (size_t)b * S_ + hi * 4;
  const int xk = (l31 & 7);             // read-side chunk XOR

  stage64b(kb + qkbase, D_, Ks[0], t);
  stage64b(vt + vtbase, S_, Vs[0], t);
  __syncthreads();
  int cur = 0;

  for (int i = 0; i < NTILE; i++) {
    f32x4 mv[2][4];
    if (!nomask) {        // mask loads FIRST (vmcnt-oldest), then prefetch
      #pragma unroll
      for (int kb2 = 0; kb2 < 2; kb2++)
        #pragma unroll
        for (int g = 0; g < 4; g++)
          mv[kb2][g] = *(const f32x4*)(mp + i * 64 + kb2 * 32 + g * 8);
      __builtin_amdgcn_sched_barrier(0);
    }
    if (i + 1 < NTILE) {  // prefetch next tile; covered by this tile's body
      stage64b(kb + qkbase + (size_t)(i + 1) * 64 * D_, D_, Ks[cur ^ 1], t);
      stage64b(vt + vtbase + (i + 1) * 64, S_, Vs[cur ^ 1], t);
    }

    // QK^T swapped: D[row=key][col=q]
    f32x16 s0, s1;
    #pragma unroll
    for (int r = 0; r < 16; r++) { s0[r] = 0.f; s1[r] = 0.f; }
    #pragma unroll
    for (int j = 0; j < 4; j++) {
      const int ch = j * 2 + hi;
      const bf16x8 kf0 = *(const bf16x8*)(&Ks[cur][0] + l31 * 64 + (ch ^ xk) * 8);
      const bf16x8 kf1 = *(const bf16x8*)(&Ks[cur][0] + (32 + l31) * 64 + (ch ^ xk) * 8);
      s0 = mfma32(kf0, qf[j], s0);
      s1 = mfma32(kf1, qf[j], s1);
    }

    float pv_[32];
    if (nomask) {
      #pragma unroll
      for (int r = 0; r < 16; r++) { pv_[r] = s0[r]; pv_[16 + r] = s1[r]; }
    } else {
      #pragma unroll
      for (int r = 0; r < 16; r++) {
        pv_[r]      = s0[r] * SCL2 + mv[0][r >> 2][r & 3];
        pv_[16 + r] = s1[r] * SCL2 + mv[1][r >> 2][r & 3];
      }
    }
    // tree max (depth 5) + pair join
    float m16[16];
    #pragma unroll
    for (int r = 0; r < 16; r++) m16[r] = fmaxf(pv_[r], pv_[16 + r]);
    #pragma unroll
    for (int r = 0; r < 8; r++) m16[r] = fmaxf(m16[r], m16[8 + r]);
    #pragma unroll
    for (int r = 0; r < 4; r++) m16[r] = fmaxf(m16[r], m16[4 + r]);
    float mx = fmaxf(fmaxf(m16[0], m16[1]), fmaxf(m16[2], m16[3]));
    mx = fmaxf(mx, __shfl_xor(mx, 32));

    const float thr = nomask ? THRR : THR;
    if (!__all(mx - mi <= thr)) {       // defer-max: rescale only when needed
      const float mnew = fmaxf(mi, mx);
      const float co = nomask ? exp2f((mi - mnew) * SCL2) : exp2f(mi - mnew);
      li *= co;
      #pragma unroll
      for (int r = 0; r < 16; r++) { ao0[r] *= co; ao1[r] *= co; }
      mi = mnew;
    }
    if (nomask) {
      const float mo = -mi * SCL2;
      #pragma unroll
      for (int r = 0; r < 32; r++) pv_[r] = exp2f(fmaf(pv_[r], SCL2, mo));
    } else {
      #pragma unroll
      for (int r = 0; r < 32; r++) pv_[r] = exp2f(pv_[r] - mi);
    }
    // tree sum
    float sm[16];
    #pragma unroll
    for (int r = 0; r < 16; r++) sm[r] = pv_[r] + pv_[16 + r];
    #pragma unroll
    for (int r = 0; r < 8; r++) sm[r] += sm[8 + r];
    #pragma unroll
    for (int r = 0; r < 4; r++) sm[r] += sm[4 + r];
    li += (sm[0] + sm[1]) + (sm[2] + sm[3]);

    // pack P -> PV B-operand frags (cvt_pk + permlane32_swap)
    unsigned pk[16];
    #pragma unroll
    for (int tt = 0; tt < 8; tt++) {
      asm("v_cvt_pk_bf16_f32 %0, %1, %2" : "=v"(pk[tt])     : "v"(pv_[2 * tt]),      "v"(pv_[2 * tt + 1]));
      asm("v_cvt_pk_bf16_f32 %0, %1, %2" : "=v"(pk[8 + tt]) : "v"(pv_[16 + 2 * tt]), "v"(pv_[16 + 2 * tt + 1]));
    }
    #pragma unroll
    for (int g = 0; g < 4; g++) {
      asm volatile("v_permlane32_swap_b32 %0, %1" : "+v"(pk[4 * g]),     "+v"(pk[4 * g + 2]));
      asm volatile("v_permlane32_swap_b32 %0, %1" : "+v"(pk[4 * g + 1]), "+v"(pk[4 * g + 3]));
    }

    // PV swapped: D[row=d][col=q]
    #pragma unroll
    for (int j = 0; j < 4; j++) {
      const u32x4 w = {pk[4 * j], pk[4 * j + 1], pk[4 * j + 2], pk[4 * j + 3]};
      const bf16x8 pf = __builtin_bit_cast(bf16x8, w);
      const int ch = j * 2 + hi;
      const bf16x8 vf0 = *(const bf16x8*)(&Vs[cur][0] + l31 * 64 + (ch ^ xk) * 8);
      const bf16x8 vf1 = *(const bf16x8*)(&Vs[cur][0] + (32 + l31) * 64 + (ch ^ xk) * 8);
      ao0 = mfma32(vf0, pf, ao0);
      ao1 = mfma32(vf1, pf, ao1);
    }
    __syncthreads();   // prefetch landed + all waves done with cur
    cur ^= 1;
  }

  // epilogue: join the hi-pair's li, normalize, write fp32, absmax
  li += __shfl_xor(li, 32);
  const float invl = 1.0f / li;
  float lmax = 0.f;
  float* orow = out + qkbase + (size_t)q * D_;
  #pragma unroll
  for (int db2 = 0; db2 < 2; db2++) {
    #pragma unroll
    for (int rg = 0; rg < 4; rg++) {
      float4 o;
      o.x = (db2 ? ao1[rg * 4 + 0] : ao0[rg * 4 + 0]) * invl;
      o.y = (db2 ? ao1[rg * 4 + 1] : ao0[rg * 4 + 1]) * invl;
      o.z = (db2 ? ao1[rg * 4 + 2] : ao0[rg * 4 + 2]) * invl;
      o.w = (db2 ? ao1[rg * 4 + 3] : ao0[rg * 4 + 3]) * invl;
      *(float4*)(orow + db2 * 32 + rg * 8 + hi * 4) = o;
      lmax = fmaxf(lmax, fmaxf(fmaxf(fabsf(o.x), fabsf(o.y)), fmaxf(fabsf(o.z), fabsf(o.w))));
    }
  }
  #pragma unroll
  for (int o = 32; o; o >>= 1) lmax = fmaxf(lmax, __shfl_xor(lmax, o));
  if (lane == 0) red[wid] = lmax;
  __syncthreads();
  if (t == 0) atomicMaxF(scal + 1, fmaxf(red[0], red[1]));
}

// ---------- launch ----------
extern "C" void kernel_launch(void* const* d_in, const int* in_sizes, int n_in,
                              void* d_out, int out_size, void* d_ws, size_t ws_size,
                              hipStream_t stream) {
  const float* hs   = (const float*)d_in[0];
  const float* mask = (const float*)d_in[1];
  const float* wq = (const float*)d_in[2];  const float* bq = (const float*)d_in[3];
  const float* wk = (const float*)d_in[4];  const float* bk = (const float*)d_in[5];
  const float* wv = (const float*)d_in[6];  const float* bv = (const float*)d_in[7];
  const float* wo = (const float*)d_in[8];  const float* bo = (const float*)d_in[9];
  const float* w1 = (const float*)d_in[10]; const float* b1 = (const float*)d_in[11];
  const float* w2 = (const float*)d_in[12]; const float* b2 = (const float*)d_in[13];
  const float* g1 = (const float*)d_in[14]; const float* be1 = (const float*)d_in[15];
  const float* g2 = (const float*)d_in[16]; const float* be2 = (const float*)d_in[17];
  const int* wbits = (const int*)d_in[18];
  const int* abits = (const int*)d_in[19];

  // workspace layout (bytes)
  char* ws = (char*)d_ws;
  size_t off = 0;
  float* scal = (float*)ws;                      off += 256;        // absmax slots + flag
  float* maddg= (float*)(ws + off);              off += (size_t)NT * 4;       // (1-mask)*MSK2
  float* fbuf = (float*)(ws + off);              off += (size_t)NT * D_ * 4;  // x1f/attnf/x2f
  bf16*  qx   = (bf16*)(ws + off);               off += (size_t)NT * D_ * 2;  // x1q/attnq/x2q
  bf16*  qb   = (bf16*)(ws + off);               off += (size_t)NT * D_ * 2;
  bf16*  kbuf = (bf16*)(ws + off);               off += (size_t)NT * D_ * 2;
  bf16*  vbuf = (bf16*)(ws + off);               off += (size_t)NT * D_ * 2;  // holds V^T
  float* h2   = (float*)(ws + off);              off += (size_t)NT * D_ * 4;  // attn residual out
  bf16*  h1   = (bf16*)(ws + off);               off += (size_t)NT * I_ * 2;  // gelu out (quant ip)
  bf16*  wqq  = (bf16*)(ws + off);               off += (size_t)D_ * D_ * 2;
  bf16*  wkq  = (bf16*)(ws + off);               off += (size_t)D_ * D_ * 2;
  bf16*  wvq  = (bf16*)(ws + off);               off += (size_t)D_ * D_ * 2;
  bf16*  woq  = (bf16*)(ws + off);               off += (size_t)D_ * D_ * 2;
  bf16*  w1q  = (bf16*)(ws + off);               off += (size_t)I_ * D_ * 2;
  bf16*  w2q  = (bf16*)(ws + off);               off += (size_t)D_ * I_ * 2;
  if (ws_size < off) return;  // insufficient workspace: fail cleanly

  // slots: 0 x1, 1 attn, 2 x2, 3 h1, 4..9 weights, 10 mask-nontrivial flag
  k_init<<<1, 64, 0, stream>>>(scal);
  k_prep<<<NT / 256, 256, 0, stream>>>(mask, maddg, scal);

  const size_t nDD4 = (size_t)D_ * D_ / 4, nDI4 = (size_t)D_ * I_ / 4;
  WArgs wa;
  wa.w[0] = wq; wa.w[1] = wk; wa.w[2] = wv; wa.w[3] = wo; wa.w[4] = w1; wa.w[5] = w2;
  wa.q[0] = wqq; wa.q[1] = wkq; wa.q[2] = wvq; wa.q[3] = woq; wa.q[4] = w1q; wa.q[5] = w2q;
  wa.n4[0] = nDD4; wa.n4[1] = nDD4; wa.n4[2] = nDD4; wa.n4[3] = nDD4;
  wa.n4[4] = nDI4; wa.n4[5] = nDI4;
  k_absmax6<<<dim3(1024, 1, 6), 256, 0, stream>>>(wa, scal + 4);
  k_quant6<<<dim3(1024, 1, 6), 256, 0, stream>>>(wa, scal + 4, wbits);

  const size_t nND4 = (size_t)NT * D_ / 4;

  // LN1 -> fake-quant -> fused QKV GEMM (V written transposed)
  k_ln<<<NT, 256, 0, stream>>>(hs, g1, be1, fbuf, scal + 0);
  k_quant<<<2048, 256, 0, stream>>>(fbuf, qx, scal + 0, abits, nND4);
  {
    GemmArgs ga{};
    ga.A = qx; ga.B0 = wqq; ga.B1 = wkq; ga.B2 = wvq;
    ga.bias0 = bq; ga.bias1 = bk; ga.bias2 = bv;
    ga.out0 = qb; ga.out1 = kbuf; ga.out2 = vbuf;
    ga.K = D_; ga.ldc = D_;
    k_gemm<0, 4><<<dim3(NT / 128, D_ / 128, 3), 256, 0, stream>>>(ga);
  }

  // attention -> fake-quant -> out-proj (+residual)
  k_attn<<<dim3(S_ / 64, B_ * H_), 128, 0, stream>>>(qb, kbuf, vbuf, maddg, fbuf, scal);
  k_quant<<<2048, 256, 0, stream>>>(fbuf, qx, scal + 1, abits, nND4);
  {
    GemmArgs ga{};
    ga.A = qx; ga.B0 = woq; ga.bias0 = bo; ga.out0 = h2; ga.res = hs;
    ga.K = D_; ga.ldc = D_;
    k_gemm<1, 2><<<dim3(NT / 64, D_ / 128), 256, 0, stream>>>(ga);
  }

  // LN2 -> fake-quant -> MLP1 (gelu + absmax) -> fake-quant -> MLP2 (+residual)
  k_ln<<<NT, 256, 0, stream>>>(h2, g2, be2, fbuf, scal + 2);
  k_quant<<<2048, 256, 0, stream>>>(fbuf, qx, scal + 2, abits, nND4);
  {
    GemmArgs ga{};
    ga.A = qx; ga.B0 = w1q; ga.bias0 = b1; ga.out0 = h1; ga.slot = scal + 3;
    ga.K = D_; ga.ldc = I_;
    k_gemm<2, 4><<<dim3(NT / 128, I_ / 128), 256, 0, stream>>>(ga);
  }
  k_quant_ip<<<(NT * (size_t)I_ / 8 + 255) / 256, 256, 0, stream>>>(h1, scal + 3, abits,
                                                                    (size_t)NT * I_ / 8);
  {
    GemmArgs ga{};
    ga.A = h1; ga.B0 = w2q; ga.bias0 = b2; ga.out0 = d_out; ga.res = h2;
    ga.K = I_; ga.ldc = D_;
    k_gemm<1, 2><<<dim3(NT / 64, D_ / 128), 256, 0, stream>>>(ga);
  }
}